// Round 11
// baseline (610.579 us; speedup 1.0000x reference)
//
#include <hip/hip_runtime.h>
#include <hip/hip_fp16.h>
#include <cstdint>
#include <initializer_list>

#define BATCH 32
#define LSEQ 1024
#define DDIM 1024

typedef unsigned short u16;
typedef unsigned int u32;
typedef __bf16 bf16x8 __attribute__((ext_vector_type(8)));
typedef float f32x4 __attribute__((ext_vector_type(4)));

__device__ __forceinline__ u16 f2bf(float f) {
  u32 u = __float_as_uint(f);
  u32 r = (u + 0x7FFFu + ((u >> 16) & 1u)) >> 16;
  return (u16)r;
}
__device__ __forceinline__ float bf2f(u16 h) {
  return __uint_as_float(((u32)h) << 16);
}
__device__ __forceinline__ float tanh_fast(float x) {
  float xx = fminf(fmaxf(x, -15.f), 15.f);
  float t = __expf(2.f * xx);
  return (t - 1.f) / (t + 1.f);
}

__device__ __forceinline__ void gload_lds16(const void* g, void* l) {
  __builtin_amdgcn_global_load_lds(
      (__attribute__((address_space(1))) void*)(uintptr_t)g,
      (__attribute__((address_space(3))) void*)(u32)(uintptr_t)l,
      16, 0, 0);
}

// ---------------- per-batch valid length from attention mask ----------------
__global__ __launch_bounds__(256) void len_kernel(const int* __restrict__ amask,
                                                  int* __restrict__ lenb) {
  int b = blockIdx.x;
  int4 m = ((const int4*)(amask + (size_t)b * LSEQ))[threadIdx.x];
  int s = m.x + m.y + m.z + m.w;
#pragma unroll
  for (int o = 32; o; o >>= 1) s += __shfl_xor(s, o);
  __shared__ int r[4];
  if ((threadIdx.x & 63) == 0) r[threadIdx.x >> 6] = s;
  __syncthreads();
  if (threadIdx.x == 0) lenb[b] = (r[0] + r[1]) + (r[2] + r[3]);
}

// ---------------- fp32 -> bf16 convert (vectorized x4) ----------------
__global__ __launch_bounds__(256) void cvt_kernel(const float* __restrict__ in,
                                                  u16* __restrict__ out, int n4) {
  int i = blockIdx.x * 256 + threadIdx.x;
  if (i >= n4) return;
  float4 f = ((const float4*)in)[i];
  ushort4 o;
  o.x = f2bf(f.x); o.y = f2bf(f.y); o.z = f2bf(f.z); o.w = f2bf(f.w);
  ((ushort4*)out)[i] = o;
}

// -- transpose+convert [L,D]f32 -> [D,L]bf16 (+[L,D]bf16 copy, +partial v-dot)
__global__ __launch_bounds__(256) void transpose_cv(const float* __restrict__ in,
                                                    u16* __restrict__ outT,
                                                    u16* __restrict__ outN,
                                                    const float* __restrict__ wv2,
                                                    float* __restrict__ vpart,
                                                    int vn) {
  __shared__ u16 tile[64][65];
  size_t boff = (size_t)blockIdx.z * (LSEQ * DDIM);
  int k0 = blockIdx.x * 64;
  int d0 = blockIdx.y * 64;
  int tx = threadIdx.x & 63;
  int ty = threadIdx.x >> 6;
  float wv = vpart ? wv2[d0 + tx] : 0.f;
#pragma unroll
  for (int r = ty; r < 64; r += 4) {
    float f = in[boff + (size_t)(k0 + r) * DDIM + d0 + tx];
    u16 h = f2bf(f);
    tile[r][tx] = h;
    if (outN) outN[boff + (size_t)(k0 + r) * DDIM + d0 + tx] = h;
    if (vpart) {
      float p = f * wv;
#pragma unroll
      for (int o = 32; o; o >>= 1) p += __shfl_xor(p, o);
      if (tx == 0) vpart[(size_t)blockIdx.y * vn + blockIdx.z * LSEQ + k0 + r] = p;
    }
  }
  __syncthreads();
#pragma unroll
  for (int r = ty; r < 64; r += 4)
    outT[boff + (size_t)(d0 + r) * LSEQ + k0 + tx] = tile[tx][r];
}

// ---- vbuf[i] = sum_s vpart[s][i] ----
__global__ __launch_bounds__(256) void vred_kernel(const float* __restrict__ vpart,
                                                   float* __restrict__ vbuf, int vn) {
  int i = blockIdx.x * 256 + threadIdx.x;
  if (i >= vn) return;
  float s = 0.f;
#pragma unroll
  for (int p = 0; p < 16; ++p) s += vpart[(size_t)p * vn + i];
  vbuf[i] = s;
}

// ---------------- out[row] = x[row,:] dot w[:]  (fp32) ----------------
__global__ __launch_bounds__(256) void rowdot_kernel(const float* __restrict__ x,
                                                     const float* __restrict__ w,
                                                     float* __restrict__ out) {
  int row = blockIdx.x;
  const float* p = x + (size_t)row * DDIM;
  int tid = threadIdx.x;
  float4 a = ((const float4*)p)[tid];
  float4 ww = ((const float4*)w)[tid];
  float s = a.x * ww.x + a.y * ww.y + a.z * ww.z + a.w * ww.w;
#pragma unroll
  for (int o = 32; o; o >>= 1) s += __shfl_xor(s, o);
  __shared__ float r[4];
  if ((tid & 63) == 0) r[tid >> 6] = s;
  __syncthreads();
  if (tid == 0) out[row] = (r[0] + r[1]) + (r[2] + r[3]);
}

// ---- wv2[d] = Wv[d] + sum_e bbo[e] * Wc[e,d] ----
__global__ __launch_bounds__(256) void w2_kernel(const float* __restrict__ Wv,
                                                 const float* __restrict__ bbo,
                                                 const float* __restrict__ Wc,
                                                 float* __restrict__ wv2) {
  int d = blockIdx.x * 256 + threadIdx.x;
  float s = Wv[d];
  for (int e = 0; e < DDIM; ++e) s += bbo[e] * Wc[(size_t)e * DDIM + d];
  wv2[d] = s;
}

// ============ small 128x128 2-phase GEMM (weight precompute only) ===========
template <int OUT_F32, int HAS_BIAS, int DO_TANH, int ZBATCH>
__global__ __launch_bounds__(256) void gemm_nt(
    const u16* __restrict__ A1, const u16* __restrict__ A2, int ksplit,
    const u16* __restrict__ Bw, const float* __restrict__ bias,
    void* __restrict__ Cout, int K, int lda, int ldb, int ldc,
    long long sA, long long sB, long long sC, int nm, int nn, int nz) {
  __shared__ u16 As[4096];
  __shared__ u16 Bs[4096];

  const int id = blockIdx.x;
  int bz, mb, nb;
  if (ZBATCH) {
    if ((nz & 7) == 0) {
      int x = id & 7; int j = id >> 3; int pb = nm * nn;
      bz = x + 8 * (j / pb);
      int in_ = j % pb; nb = in_ % nn; mb = in_ / nn;
    } else { bz = id % nz; int t = id / nz; nb = t % nn; mb = t / nn; }
  } else {
    bz = 0;
    if ((nm & 7) == 0) {
      int mg = id & 7; int t = id >> 3; int nmg = nm >> 3;
      nb = t % nn; mb = mg * nmg + t / nn;
    } else { nb = id % nn; mb = id / nn; }
  }

  const int tid = threadIdx.x;
  const int lane = tid & 63;
  const int wid = tid >> 6;
  const int wm = wid >> 1;
  const int wn = wid & 1;
  const int m0 = mb * 128;
  const int n0 = nb * 128;

  const u16* a1 = A1 + (size_t)bz * sA;
  const u16* a2 = A2 + (size_t)bz * sA;
  const u16* bw = Bw + (size_t)bz * sB;

  const int srow = wid * 16 + (lane >> 2);
  const int skof = (lane & 3) * 8;

  f32x4 acc[4][4] = {};

  for (int k0 = 0; k0 < K; k0 += 32) {
    const u16* ab; int kk;
    if (k0 < ksplit) { ab = a1; kk = k0; } else { ab = a2; kk = k0 - ksplit; }
    const u16* asrc = ab + (size_t)(m0 + srow) * lda + kk + skof;
    const u16* bsrc = bw + (size_t)(n0 + srow) * ldb + k0 + skof;
    gload_lds16(asrc, &As[wid * 512]);
    gload_lds16(asrc + (size_t)64 * lda, &As[2048 + wid * 512]);
    gload_lds16(bsrc, &Bs[wid * 512]);
    gload_lds16(bsrc + (size_t)64 * ldb, &Bs[2048 + wid * 512]);
    __syncthreads();

    bf16x8 af[4], bfv[4];
#pragma unroll
    for (int i = 0; i < 4; ++i) {
      af[i] = *(const bf16x8*)&As[(wm * 64 + i * 16 + (lane & 15)) * 32 + (lane >> 4) * 8];
      bfv[i] = *(const bf16x8*)&Bs[(wn * 64 + i * 16 + (lane & 15)) * 32 + (lane >> 4) * 8];
    }
#pragma unroll
    for (int i = 0; i < 4; ++i)
#pragma unroll
      for (int j = 0; j < 4; ++j)
        acc[i][j] = __builtin_amdgcn_mfma_f32_16x16x32_bf16(af[i], bfv[j], acc[i][j], 0, 0, 0);
    __syncthreads();
  }

  const int crow = (lane >> 4) * 4;
  const int ccol = lane & 15;
#pragma unroll
  for (int i = 0; i < 4; ++i) {
#pragma unroll
    for (int j = 0; j < 4; ++j) {
      int r0 = m0 + wm * 64 + i * 16 + crow;
      int c = n0 + wn * 64 + j * 16 + ccol;
      float bb = HAS_BIAS ? bias[c] : 0.f;
#pragma unroll
      for (int t = 0; t < 4; ++t) {
        float v = acc[i][j][t] + bb;
        if (DO_TANH) v = tanh_fast(v);
        size_t idx = (size_t)bz * sC + (size_t)(r0 + t) * ldc + c;
        if (OUT_F32) ((float*)Cout)[idx] = v;
        else ((u16*)Cout)[idx] = f2bf(v);
      }
    }
  }
}

// ==== 256x128 GEMM, 2 blocks/CU: 4 waves (128x64 each), BK=32, 2 dbuf ====
// 48 KiB LDS; stages issued at tile start (full tile to land); counted
// lgkmcnt(4) overlaps ph2 reads under ph1 MFMA; vmcnt(0)+barrier per tile.
// MASK bits: 1=skip dead m, 2=skip dead n, 4=truncate K (32-granule).
// OUTT: 0=f32, 1=bf16, 2=f16. POOL=1: fused masked pooling epilogue -> pf.
template <int OUTT, int HAS_BIAS, int DO_TANH, int ZBATCH, int MASK, int POOL>
__global__ __launch_bounds__(256, 2) void gemm2b(
    const u16* __restrict__ A1, const u16* __restrict__ A2, int ksplit,
    const u16* __restrict__ Bw, const float* __restrict__ bias, long long sBias,
    void* __restrict__ Cout, int K, int lda, int ldb, int ldc,
    long long sA, long long sB, long long sC, int nm, int nn, int nz,
    const int* __restrict__ lenb, float* __restrict__ pf) {
  __shared__ __align__(16) u16 A0[8192];   // 16 KiB: 16 subtiles x [16][32]
  __shared__ __align__(16) u16 A1s[8192];
  __shared__ __align__(16) u16 B0[4096];   // 8 KiB: 8 subtiles
  __shared__ __align__(16) u16 B1s[4096];

  const int id = blockIdx.x;
  int bz, mb, nb;
  if (ZBATCH) {
    if ((nz & 7) == 0) {
      int x = id & 7; int j = id >> 3; int pb = nm * nn;
      bz = x + 8 * (j / pb);
      int in_ = j % pb; nb = in_ % nn; mb = in_ / nn;
    } else { bz = id % nz; int t = id / nz; nb = t % nn; mb = t / nn; }
  } else {
    bz = 0;
    if ((nm & 7) == 0) {
      int mg = id & 7; int t = id >> 3; int nmg = nm >> 3;
      nb = t % nn; mb = mg * nmg + t / nn;
    } else { nb = id % nn; mb = id / nn; }
  }

  const int m0 = mb * 256;
  const int n0 = nb * 128;

  int Keff = K;
  if (MASK) {
    if (MASK & 1) {
      int lb = ZBATCH ? bz : (m0 >> 10);
      int lm = ZBATCH ? m0 : (m0 & 1023);
      if (lm >= lenb[lb]) return;
    }
    if (MASK & 2) {
      if (n0 >= lenb[bz]) return;
    }
    if (MASK & 4) {
      Keff = (lenb[bz] + 31) & ~31;
    }
  }
  const int NT = Keff >> 5;  // K-tiles of 32

  const int tid = threadIdx.x;
  const int lane = tid & 63;
  const int wid = tid >> 6;  // 0..3
  const int wm = wid >> 1;   // 0..1 : 128-row half
  const int wn = wid & 1;    // 0..1 : 64-col half
  const u16* a1 = A1 + (size_t)bz * sA;
  const u16* a2 = A2 + (size_t)bz * sA;
  const u16* bw = Bw + (size_t)bz * sB;

  // staging: 1 gload = 1 subtile (64 lanes x 16B = 1 KiB).
  // LDS linear: row = lane>>2, slot = lane&3; that slot holds global slot
  // (slot ^ (row&3)) -> inverse-swizzled source column.
  const int stR = lane >> 2;
  const int stS = (((lane & 3) ^ ((lane >> 2) & 3))) * 8;  // u16 units

  // fragment read: row frr = lane&15, logical k-slot q=(lane>>4)&3 stored at
  // slot q^(frr&3)
  const int frr = lane & 15;
  const int fo = frr * 32 + ((((lane >> 4) & 3) ^ (frr & 3)) * 8);

  f32x4 acc[8][4] = {};

#define STG_A(tt, buf, st)                                                   \
  do {                                                                       \
    int kb = (tt) << 5; const u16* g; int gk;                                \
    if (kb < ksplit) { g = a1; gk = kb; } else { g = a2; gk = kb - ksplit; } \
    gload_lds16(g + (size_t)(m0 + (st) * 16 + stR) * lda + gk + stS,         \
                (buf) + (st) * 512);                                         \
  } while (0)
#define STG_B(tt, buf, st)                                                   \
  do {                                                                       \
    int kb = (tt) << 5;                                                      \
    gload_lds16(bw + (size_t)(n0 + (st) * 16 + stR) * ldb + kb + stS,        \
                (buf) + (st) * 512);                                         \
  } while (0)
#define WAITL(n)                                                             \
  do {                                                                       \
    asm volatile("s_waitcnt lgkmcnt(" #n ")" ::: "memory");                  \
    __builtin_amdgcn_sched_barrier(0);                                       \
  } while (0)
#define MM4(base, ar)                                                        \
  do {                                                                       \
    __builtin_amdgcn_s_setprio(1);                                           \
    _Pragma("unroll") for (int i = 0; i < 4; ++i)                            \
    _Pragma("unroll") for (int n = 0; n < 4; ++n)                            \
      acc[(base) + i][n] = __builtin_amdgcn_mfma_f32_16x16x32_bf16(          \
          ar[i], bfr[n], acc[(base) + i][n], 0, 0, 0);                       \
    __builtin_amdgcn_s_setprio(0);                                           \
  } while (0)

#define TILE(t, Ab, Bb, An, Bn)                                              \
  do {                                                                       \
    const bool stg = (t) + 1 < NT;                                           \
    if (stg) {                                                               \
      STG_A((t) + 1, An, wid);                                               \
      STG_A((t) + 1, An, wid + 4);                                           \
      STG_A((t) + 1, An, wid + 8);                                           \
      STG_A((t) + 1, An, wid + 12);                                          \
      STG_B((t) + 1, Bn, wid);                                               \
      STG_B((t) + 1, Bn, wid + 4);                                           \
    }                                                                        \
    bf16x8 bfr[4], aA[4], aB[4];                                             \
    _Pragma("unroll") for (int n = 0; n < 4; ++n)                            \
      bfr[n] = *(const bf16x8*)((Bb) + (wn * 4 + n) * 512 + fo);             \
    _Pragma("unroll") for (int i = 0; i < 4; ++i)                            \
      aA[i] = *(const bf16x8*)((Ab) + (wm * 8 + i) * 512 + fo);              \
    _Pragma("unroll") for (int i = 0; i < 4; ++i)                            \
      aB[i] = *(const bf16x8*)((Ab) + (wm * 8 + 4 + i) * 512 + fo);          \
    WAITL(4);                                                                \
    MM4(0, aA);                                                              \
    WAITL(0);                                                                \
    MM4(4, aB);                                                              \
    asm volatile("s_waitcnt vmcnt(0)" ::: "memory");                         \
    __builtin_amdgcn_s_barrier();                                            \
    __builtin_amdgcn_sched_barrier(0);                                       \
  } while (0)

  // prologue: stage tile 0
  STG_A(0, A0, wid); STG_A(0, A0, wid + 4);
  STG_A(0, A0, wid + 8); STG_A(0, A0, wid + 12);
  STG_B(0, B0, wid); STG_B(0, B0, wid + 4);
  asm volatile("s_waitcnt vmcnt(0)" ::: "memory");
  __builtin_amdgcn_s_barrier();

  for (int t = 0; t < NT; t += 2) {
    TILE(t, A0, B0, A1s, B1s);
    if (t + 1 < NT) TILE(t + 1, A1s, B1s, A0, B0);
  }
#undef TILE
#undef MM4
#undef WAITL
#undef STG_A
#undef STG_B

  const int crow = (lane >> 4) * 4;
  const int ccol = lane & 15;

  if (POOL) {
    // fused masked pooling: per-column sums of tanh(acc + bias) over live rows
    const int b = m0 >> 10;
    const int lenv = lenb[b];
    const int qbase = (m0 & 1023) + wm * 128 + crow;
    float csum[4] = {0.f, 0.f, 0.f, 0.f};
#pragma unroll
    for (int j = 0; j < 4; ++j) {
      int c = n0 + wn * 64 + j * 16 + ccol;
      float bb = bias[c];
#pragma unroll
      for (int i = 0; i < 8; ++i) {
#pragma unroll
        for (int t = 0; t < 4; ++t) {
          int q = qbase + i * 16 + t;
          float v = tanh_fast(acc[i][j][t] + bb);
          csum[j] += (q < lenv) ? v : 0.f;
        }
      }
    }
    float* red = (float*)A0;  // [wm*2+wn][64] = 1 KB (LDS reuse after loop)
#pragma unroll
    for (int j = 0; j < 4; ++j) {
      float cs = csum[j];
      cs += __shfl_xor(cs, 16);
      cs += __shfl_xor(cs, 32);
      if (lane < 16) red[(wm * 2 + wn) * 64 + j * 16 + lane] = cs;
    }
    __syncthreads();
    if (tid < 128) {
      int wnn = tid >> 6, cl = tid & 63;
      float v = red[(0 * 2 + wnn) * 64 + cl] + red[(1 * 2 + wnn) * 64 + cl];
      pf[(size_t)mb * 1024 + n0 + wnn * 64 + cl] = v;
    }
    return;
  }

#pragma unroll
  for (int i = 0; i < 8; ++i) {
#pragma unroll
    for (int j = 0; j < 4; ++j) {
      int r0 = m0 + wm * 128 + i * 16 + crow;
      int c = n0 + wn * 64 + j * 16 + ccol;
      float bb = HAS_BIAS ? bias[(size_t)bz * sBias + c] : 0.f;
#pragma unroll
      for (int t = 0; t < 4; ++t) {
        float v = acc[i][j][t] + bb;
        if (DO_TANH) v = tanh_fast(v);
        size_t idx = (size_t)bz * sC + (size_t)(r0 + t) * ldc + c;
        if (OUTT == 0) {
          ((float*)Cout)[idx] = v;
        } else if (OUTT == 1) {
          ((u16*)Cout)[idx] = f2bf(v);
        } else {
          __half hv = __float2half(v);
          ((u16*)Cout)[idx] = __half_as_ushort(hv);
        }
      }
    }
  }
}

// -------- softmax over keys (mask); logits fp16 already include v-bias ------
__global__ __launch_bounds__(256) void softmax_rows(const u16* __restrict__ logits,
                                                    const int* __restrict__ amask,
                                                    u16* __restrict__ P,
                                                    const int* __restrict__ lenb) {
  const int row = blockIdx.x;  // blocal*L + q
  const int b = row >> 10;
  const int q = row & 1023;
  if (q >= lenb[b]) return;  // dead query row: P never read downstream
  const u16* lg = logits + (size_t)row * LSEQ;
  u16* prow = P + (size_t)row * LSEQ;
  const int tid = threadIdx.x;

  ushort4 lraw = ((const ushort4*)lg)[tid];
  int4 mk4 = ((const int4*)(amask + (b << 10)))[tid];

  float x[4];
  int mk[4] = {mk4.x, mk4.y, mk4.z, mk4.w};
  x[0] = __half2float(__ushort_as_half(lraw.x));
  x[1] = __half2float(__ushort_as_half(lraw.y));
  x[2] = __half2float(__ushort_as_half(lraw.z));
  x[3] = __half2float(__ushort_as_half(lraw.w));

  float vmax = -3.0e38f;
#pragma unroll
  for (int i = 0; i < 4; ++i) {
    if (!mk[i]) x[i] = -3.0e38f;
    vmax = fmaxf(vmax, x[i]);
  }
#pragma unroll
  for (int o = 32; o; o >>= 1) vmax = fmaxf(vmax, __shfl_xor(vmax, o));
  __shared__ float sred[4];
  if ((tid & 63) == 0) sred[tid >> 6] = vmax;
  __syncthreads();
  vmax = fmaxf(fmaxf(sred[0], sred[1]), fmaxf(sred[2], sred[3]));
  float s = 0.f, e[4];
#pragma unroll
  for (int i = 0; i < 4; ++i) {
    e[i] = mk[i] ? __expf(x[i] - vmax) : 0.f;
    s += e[i];
  }
#pragma unroll
  for (int o = 32; o; o >>= 1) s += __shfl_xor(s, o);
  __shared__ float ssum[4];
  if ((tid & 63) == 0) ssum[tid >> 6] = s;
  __syncthreads();
  s = (ssum[0] + ssum[1]) + (ssum[2] + ssum[3]);
  float inv = 1.f / s;
  ushort4 o4;
  o4.x = f2bf(e[0] * inv);
  o4.y = f2bf(e[1] * inv);
  o4.z = f2bf(e[2] * inv);
  o4.w = f2bf(e[3] * inv);
  ((ushort4*)prow)[tid] = o4;
}

// ------- final pooling: sum live pf chunks, divide by length -------
__global__ __launch_bounds__(256) void pool_final(const float* __restrict__ pf,
                                                  const int* __restrict__ lenb,
                                                  float* __restrict__ out) {
  int idx = blockIdx.x * 256 + threadIdx.x;  // b*D + d
  int b = idx >> 10;
  int d = idx & 1023;
  int len = lenb[b];
  float s = 0.f;
#pragma unroll
  for (int qc = 0; qc < 4; ++qc)
    if (qc * 256 < len) s += pf[(size_t)(b * 4 + qc) * 1024 + d];
  out[idx] = s / (float)len;
}

extern "C" void kernel_launch(void* const* d_in, const int* in_sizes, int n_in,
                              void* d_out, int out_size, void* d_ws, size_t ws_size,
                              hipStream_t stream) {
  const float* output = (const float*)d_in[0];
  const float* context = (const float*)d_in[1];
  const int* amask = (const int*)d_in[2];
  const float* Wo = (const float*)d_in[3];
  const float* bo = (const float*)d_in[4];
  const float* Wc = (const float*)d_in[5];
  const float* Wb = (const float*)d_in[7];
  const float* Wv = (const float*)d_in[10];
  const float* Wf = (const float*)d_in[12];
  const float* bfb = (const float*)d_in[13];
  float* out = (float*)d_out;
  (void)n_in; (void)in_sizes; (void)out_size;

  const size_t LD2 = (size_t)LSEQ * DDIM * 2;
  const size_t fixed_b = (size_t)24 * (1 << 20);
  const size_t per_b = 4 * LD2 + (size_t)LSEQ * LSEQ * 2 + 80 * LSEQ + 4096;
  int G = 1;
  for (int g : {32, 16, 8, 4, 2, 1}) {
    if (fixed_b + (size_t)g * per_b <= ws_size) { G = g; break; }
  }
  const int NG = BATCH / G;
  const int VN = G * LSEQ;

  char* ws = (char*)d_ws;
  size_t off = 0;
  auto alloc = [&](size_t bytes) {
    char* p = ws + off;
    off += (bytes + 255) & ~(size_t)255;
    return p;
  };
  const size_t W2 = (size_t)DDIM * DDIM * 2;
  u16* wb_bf = (u16*)alloc(W2);
  u16* wf_bf = (u16*)alloc(2 * W2);
  u16* woT_bf = (u16*)alloc(W2);
  u16* wcT_bf = (u16*)alloc(W2);
  u16* wboT_bf = (u16*)alloc(W2);
  u16* mt_bf = (u16*)alloc(W2);
  float* bbo = (float*)alloc(DDIM * 4);
  float* wv2 = (float*)alloc(DDIM * 4);
  int* lenb = (int*)alloc(BATCH * 4);
  float* pf = (float*)alloc((size_t)BATCH * 4 * DDIM * 4);  // [B*4][1024]
  u16* out_g = (u16*)alloc((size_t)G * LD2);
  u16* ctx_g = (u16*)alloc((size_t)G * LD2);
  u16* ctxT_g = (u16*)alloc((size_t)G * LD2);
  u16* y_g = (u16*)alloc((size_t)G * LD2);
  u16* logits = (u16*)alloc((size_t)G * LSEQ * LSEQ * 2);  // fp16
  float* vbuf = (float*)alloc((size_t)VN * 4);
  float* vpart = (float*)alloc((size_t)16 * VN * 4);

  dim3 blk(256);
  const long long M1 = (long long)LSEQ * DDIM;
  const int BIG = 1 << 30;

  // ---- lengths + weight precompute ----
  len_kernel<<<dim3(BATCH), blk, 0, stream>>>(amask, lenb);
  cvt_kernel<<<dim3(1024), blk, 0, stream>>>(Wb, wb_bf, DDIM * DDIM / 4);
  cvt_kernel<<<dim3(2048), blk, 0, stream>>>(Wf, wf_bf, DDIM * 2 * DDIM / 4);
  transpose_cv<<<dim3(16, 16, 1), blk, 0, stream>>>(Wo, woT_bf, nullptr, nullptr, nullptr, 0);
  transpose_cv<<<dim3(16, 16, 1), blk, 0, stream>>>(Wc, wcT_bf, nullptr, nullptr, nullptr, 0);
  rowdot_kernel<<<dim3(1024), blk, 0, stream>>>(Wb, bo, bbo);
  w2_kernel<<<dim3(4), blk, 0, stream>>>(Wv, bbo, Wc, wv2);
  gemm_nt<0, 0, 0, 0><<<dim3(64), blk, 0, stream>>>(
      woT_bf, woT_bf, BIG, wb_bf, nullptr, wboT_bf,
      1024, 1024, 1024, 1024, 0, 0, 0, 8, 8, 1);
  gemm_nt<0, 0, 0, 0><<<dim3(64), blk, 0, stream>>>(
      wcT_bf, wcT_bf, BIG, wboT_bf, nullptr, mt_bf,
      1024, 1024, 1024, 1024, 0, 0, 0, 8, 8, 1);

  for (int grp = 0; grp < NG; ++grp) {
    const int gb = grp * G;
    const float* outp = output + (size_t)gb * LSEQ * DDIM;
    const float* ctxp = context + (size_t)gb * LSEQ * DDIM;
    const int* amp = amask + (size_t)gb * LSEQ;
    const int* lnp = lenb + gb;
    const int n4 = G * LSEQ * DDIM / 4;

    cvt_kernel<<<dim3(n4 / 256), blk, 0, stream>>>(outp, out_g, n4);
    // transpose + bf16 copy + fused partial v-dot
    transpose_cv<<<dim3(16, 16, G), blk, 0, stream>>>(ctxp, ctxT_g, ctx_g, wv2, vpart, VN);
    vred_kernel<<<dim3(VN / 256), blk, 0, stream>>>(vpart, vbuf, VN);

    // y = output @ M   [dense, bf16 out; skip dead q-blocks]
    gemm2b<1, 0, 0, 0, 1, 0><<<dim3(G * 32), blk, 0, stream>>>(
        out_g, out_g, BIG, mt_bf, nullptr, 0, y_g,
        1024, 1024, 1024, 1024, 0, 0, 0, G * 4, 8, 1, lnp, nullptr);
    // logits[b] = y[b] @ ctx[b]^T + v[k]  [fp16 out; skip dead m,n blocks]
    gemm2b<2, 1, 0, 1, 3, 0><<<dim3(G * 32), blk, 0, stream>>>(
        y_g, y_g, BIG, ctx_g, vbuf, 1024, logits,
        1024, 1024, 1024, 1024, M1, M1, M1, 4, 8, G, lnp, nullptr);
    // P = softmax(logits + mask) -> bf16 into y_g (skip dead rows)
    softmax_rows<<<dim3(G * LSEQ), blk, 0, stream>>>(logits, amp, y_g, lnp);
    // mix[b] = P[b] @ ctxT[b]^T -> bf16 into ctx_g (skip dead m; truncate K)
    gemm2b<1, 0, 0, 1, 5, 0><<<dim3(G * 32), blk, 0, stream>>>(
        y_g, y_g, BIG, ctxT_g, nullptr, 0, ctx_g,
        1024, 1024, 1024, 1024, M1, M1, M1, 4, 8, G, lnp, nullptr);
    // fc + fused masked pooling: tanh([out, mix] @ Wf^T + bf) summed -> pf
    gemm2b<1, 1, 1, 0, 1, 1><<<dim3(G * 32), blk, 0, stream>>>(
        out_g, ctx_g, 1024, wf_bf, bfb, 0, nullptr,
        2048, 1024, 2048, 1024, 0, 0, 0, G * 4, 8, 1, lnp,
        pf + (size_t)gb * 4 * DDIM);
  }
  pool_final<<<dim3(128), blk, 0, stream>>>(pf, lenb, out);
}

// Round 12
// 577.373 us; speedup vs baseline: 1.0575x; 1.0575x over previous
//
#include <hip/hip_runtime.h>
#include <hip/hip_fp16.h>
#include <cstdint>
#include <initializer_list>

#define BATCH 32
#define LSEQ 1024
#define DDIM 1024

typedef unsigned short u16;
typedef unsigned int u32;
typedef __bf16 bf16x8 __attribute__((ext_vector_type(8)));
typedef float f32x4 __attribute__((ext_vector_type(4)));

__device__ __forceinline__ u16 f2bf(float f) {
  u32 u = __float_as_uint(f);
  u32 r = (u + 0x7FFFu + ((u >> 16) & 1u)) >> 16;
  return (u16)r;
}
__device__ __forceinline__ float bf2f(u16 h) {
  return __uint_as_float(((u32)h) << 16);
}
__device__ __forceinline__ float tanh_fast(float x) {
  float xx = fminf(fmaxf(x, -15.f), 15.f);
  float t = __expf(2.f * xx);
  return (t - 1.f) / (t + 1.f);
}

__device__ __forceinline__ void gload_lds16(const void* g, void* l) {
  __builtin_amdgcn_global_load_lds(
      (__attribute__((address_space(1))) void*)(uintptr_t)g,
      (__attribute__((address_space(3))) void*)(u32)(uintptr_t)l,
      16, 0, 0);
}

// ---------------- per-batch valid length from attention mask ----------------
__global__ __launch_bounds__(256) void len_kernel(const int* __restrict__ amask,
                                                  int* __restrict__ lenb) {
  int b = blockIdx.x;
  int4 m = ((const int4*)(amask + (size_t)b * LSEQ))[threadIdx.x];
  int s = m.x + m.y + m.z + m.w;
#pragma unroll
  for (int o = 32; o; o >>= 1) s += __shfl_xor(s, o);
  __shared__ int r[4];
  if ((threadIdx.x & 63) == 0) r[threadIdx.x >> 6] = s;
  __syncthreads();
  if (threadIdx.x == 0) lenb[b] = (r[0] + r[1]) + (r[2] + r[3]);
}

// ---------------- fp32 -> bf16 convert (vectorized x4) ----------------
__global__ __launch_bounds__(256) void cvt_kernel(const float* __restrict__ in,
                                                  u16* __restrict__ out, int n4) {
  int i = blockIdx.x * 256 + threadIdx.x;
  if (i >= n4) return;
  float4 f = ((const float4*)in)[i];
  ushort4 o;
  o.x = f2bf(f.x); o.y = f2bf(f.y); o.z = f2bf(f.z); o.w = f2bf(f.w);
  ((ushort4*)out)[i] = o;
}

// -- transpose+convert [L,D]f32 -> [D,L]bf16 (+[L,D]bf16 copy, +partial v-dot)
__global__ __launch_bounds__(256) void transpose_cv(const float* __restrict__ in,
                                                    u16* __restrict__ outT,
                                                    u16* __restrict__ outN,
                                                    const float* __restrict__ wv2,
                                                    float* __restrict__ vpart,
                                                    int vn) {
  __shared__ u16 tile[64][65];
  size_t boff = (size_t)blockIdx.z * (LSEQ * DDIM);
  int k0 = blockIdx.x * 64;
  int d0 = blockIdx.y * 64;
  int tx = threadIdx.x & 63;
  int ty = threadIdx.x >> 6;
  float wv = vpart ? wv2[d0 + tx] : 0.f;
#pragma unroll
  for (int r = ty; r < 64; r += 4) {
    float f = in[boff + (size_t)(k0 + r) * DDIM + d0 + tx];
    u16 h = f2bf(f);
    tile[r][tx] = h;
    if (outN) outN[boff + (size_t)(k0 + r) * DDIM + d0 + tx] = h;
    if (vpart) {
      float p = f * wv;
#pragma unroll
      for (int o = 32; o; o >>= 1) p += __shfl_xor(p, o);
      if (tx == 0) vpart[(size_t)blockIdx.y * vn + blockIdx.z * LSEQ + k0 + r] = p;
    }
  }
  __syncthreads();
#pragma unroll
  for (int r = ty; r < 64; r += 4)
    outT[boff + (size_t)(d0 + r) * LSEQ + k0 + tx] = tile[tx][r];
}

// ---- vbuf[i] = sum_s vpart[s][i] ----
__global__ __launch_bounds__(256) void vred_kernel(const float* __restrict__ vpart,
                                                   float* __restrict__ vbuf, int vn) {
  int i = blockIdx.x * 256 + threadIdx.x;
  if (i >= vn) return;
  float s = 0.f;
#pragma unroll
  for (int p = 0; p < 16; ++p) s += vpart[(size_t)p * vn + i];
  vbuf[i] = s;
}

// ---------------- out[row] = x[row,:] dot w[:]  (fp32) ----------------
__global__ __launch_bounds__(256) void rowdot_kernel(const float* __restrict__ x,
                                                     const float* __restrict__ w,
                                                     float* __restrict__ out) {
  int row = blockIdx.x;
  const float* p = x + (size_t)row * DDIM;
  int tid = threadIdx.x;
  float4 a = ((const float4*)p)[tid];
  float4 ww = ((const float4*)w)[tid];
  float s = a.x * ww.x + a.y * ww.y + a.z * ww.z + a.w * ww.w;
#pragma unroll
  for (int o = 32; o; o >>= 1) s += __shfl_xor(s, o);
  __shared__ float r[4];
  if ((tid & 63) == 0) r[tid >> 6] = s;
  __syncthreads();
  if (tid == 0) out[row] = (r[0] + r[1]) + (r[2] + r[3]);
}

// ---- wv2[d] = Wv[d] + sum_e bbo[e] * Wc[e,d] ----
__global__ __launch_bounds__(256) void w2_kernel(const float* __restrict__ Wv,
                                                 const float* __restrict__ bbo,
                                                 const float* __restrict__ Wc,
                                                 float* __restrict__ wv2) {
  int d = blockIdx.x * 256 + threadIdx.x;
  float s = Wv[d];
  for (int e = 0; e < DDIM; ++e) s += bbo[e] * Wc[(size_t)e * DDIM + d];
  wv2[d] = s;
}

// ============ small 128x128 2-phase GEMM (weight precompute only) ===========
template <int OUT_F32, int HAS_BIAS, int DO_TANH, int ZBATCH>
__global__ __launch_bounds__(256) void gemm_nt(
    const u16* __restrict__ A1, const u16* __restrict__ A2, int ksplit,
    const u16* __restrict__ Bw, const float* __restrict__ bias,
    void* __restrict__ Cout, int K, int lda, int ldb, int ldc,
    long long sA, long long sB, long long sC, int nm, int nn, int nz) {
  __shared__ u16 As[4096];
  __shared__ u16 Bs[4096];

  const int id = blockIdx.x;
  int bz, mb, nb;
  if (ZBATCH) {
    if ((nz & 7) == 0) {
      int x = id & 7; int j = id >> 3; int pb = nm * nn;
      bz = x + 8 * (j / pb);
      int in_ = j % pb; nb = in_ % nn; mb = in_ / nn;
    } else { bz = id % nz; int t = id / nz; nb = t % nn; mb = t / nn; }
  } else {
    bz = 0;
    if ((nm & 7) == 0) {
      int mg = id & 7; int t = id >> 3; int nmg = nm >> 3;
      nb = t % nn; mb = mg * nmg + t / nn;
    } else { nb = id % nn; mb = id / nn; }
  }

  const int tid = threadIdx.x;
  const int lane = tid & 63;
  const int wid = tid >> 6;
  const int wm = wid >> 1;
  const int wn = wid & 1;
  const int m0 = mb * 128;
  const int n0 = nb * 128;

  const u16* a1 = A1 + (size_t)bz * sA;
  const u16* a2 = A2 + (size_t)bz * sA;
  const u16* bw = Bw + (size_t)bz * sB;

  const int srow = wid * 16 + (lane >> 2);
  const int skof = (lane & 3) * 8;

  f32x4 acc[4][4] = {};

  for (int k0 = 0; k0 < K; k0 += 32) {
    const u16* ab; int kk;
    if (k0 < ksplit) { ab = a1; kk = k0; } else { ab = a2; kk = k0 - ksplit; }
    const u16* asrc = ab + (size_t)(m0 + srow) * lda + kk + skof;
    const u16* bsrc = bw + (size_t)(n0 + srow) * ldb + k0 + skof;
    gload_lds16(asrc, &As[wid * 512]);
    gload_lds16(asrc + (size_t)64 * lda, &As[2048 + wid * 512]);
    gload_lds16(bsrc, &Bs[wid * 512]);
    gload_lds16(bsrc + (size_t)64 * ldb, &Bs[2048 + wid * 512]);
    __syncthreads();

    bf16x8 af[4], bfv[4];
#pragma unroll
    for (int i = 0; i < 4; ++i) {
      af[i] = *(const bf16x8*)&As[(wm * 64 + i * 16 + (lane & 15)) * 32 + (lane >> 4) * 8];
      bfv[i] = *(const bf16x8*)&Bs[(wn * 64 + i * 16 + (lane & 15)) * 32 + (lane >> 4) * 8];
    }
#pragma unroll
    for (int i = 0; i < 4; ++i)
#pragma unroll
      for (int j = 0; j < 4; ++j)
        acc[i][j] = __builtin_amdgcn_mfma_f32_16x16x32_bf16(af[i], bfv[j], acc[i][j], 0, 0, 0);
    __syncthreads();
  }

  const int crow = (lane >> 4) * 4;
  const int ccol = lane & 15;
#pragma unroll
  for (int i = 0; i < 4; ++i) {
#pragma unroll
    for (int j = 0; j < 4; ++j) {
      int r0 = m0 + wm * 64 + i * 16 + crow;
      int c = n0 + wn * 64 + j * 16 + ccol;
      float bb = HAS_BIAS ? bias[c] : 0.f;
#pragma unroll
      for (int t = 0; t < 4; ++t) {
        float v = acc[i][j][t] + bb;
        if (DO_TANH) v = tanh_fast(v);
        size_t idx = (size_t)bz * sC + (size_t)(r0 + t) * ldc + c;
        if (OUT_F32) ((float*)Cout)[idx] = v;
        else ((u16*)Cout)[idx] = f2bf(v);
      }
    }
  }
}

// ======= 256x256 8-phase GEMM (round-8 schedule: per-phase barrier,
// counted vmcnt(4)/vmcnt(2), st swizzle). MASK bits: 1=skip dead m,
// 2=skip dead n, 4=truncate K. OUTT: 0=f32, 1=bf16, 2=f16.
// POOL=1: fused masked pooling epilogue (tanh + per-column sums -> pf),
// no C write. bias indexed bias[bz*sBias + c].
template <int OUTT, int HAS_BIAS, int DO_TANH, int ZBATCH, int MASK, int POOL>
__global__ __launch_bounds__(512, 1) void gemm8p(
    const u16* __restrict__ A1, const u16* __restrict__ A2, int ksplit,
    const u16* __restrict__ Bw, const float* __restrict__ bias, long long sBias,
    void* __restrict__ Cout, int K, int lda, int ldb, int ldc,
    long long sA, long long sB, long long sC, int nm, int nn, int nz,
    const int* __restrict__ lenb, float* __restrict__ pf) {
  __shared__ __align__(16) u16 A0[16384];
  __shared__ __align__(16) u16 A1s[16384];
  __shared__ __align__(16) u16 B0[16384];
  __shared__ __align__(16) u16 B1s[16384];

  const int id = blockIdx.x;
  int bz, mb, nb;
  if (ZBATCH) {
    if ((nz & 7) == 0) {
      int x = id & 7; int j = id >> 3; int pb = nm * nn;
      bz = x + 8 * (j / pb);
      int in_ = j % pb; nb = in_ % nn; mb = in_ / nn;
    } else { bz = id % nz; int t = id / nz; nb = t % nn; mb = t / nn; }
  } else {
    bz = 0;
    if ((nm & 7) == 0) {
      int mg = id & 7; int t = id >> 3; int nmg = nm >> 3;
      nb = t % nn; mb = mg * nmg + t / nn;
    } else { nb = id % nn; mb = id / nn; }
  }

  const int m0 = mb * 256;
  const int n0 = nb * 256;

  int Keff = K;
  if (MASK) {
    if (MASK & 1) {
      int lb = ZBATCH ? bz : (m0 >> 10);
      int lm = ZBATCH ? m0 : (m0 & 1023);
      if (lm >= lenb[lb]) return;
    }
    if (MASK & 2) {
      if (n0 >= lenb[bz]) return;
    }
    if (MASK & 4) {
      Keff = (lenb[bz] + 63) & ~63;
    }
  }
  const int NT = Keff >> 6;  // K-tiles of 64

  const int tid = threadIdx.x;
  const int lane = tid & 63;
  const int wid = tid >> 6;  // 0..7
  const int wm = wid >> 2;   // 0..1 : 128-row half
  const int wn = wid & 3;    // 0..3 : 64-col quarter

  const u16* a1 = A1 + (size_t)bz * sA;
  const u16* a2 = A2 + (size_t)bz * sA;
  const u16* bw = Bw + (size_t)bz * sB;

  const int stR = lane >> 3;
  const int stS = ((lane & 7) ^ (lane >> 3)) * 8;  // u16 units
  const int a1w = (wid < 4) ? wid : 4 + wid;
  const int a2w = (wid < 4) ? 4 + wid : 8 + wid;

  const int frr = lane & 15;
  const int fo0 = frr * 64 + (((lane >> 4)) ^ (frr & 7)) * 8;
  const int fo1 = frr * 64 + ((4 + (lane >> 4)) ^ (frr & 7)) * 8;

  f32x4 acc[8][4] = {};

#define STG_A(tt, buf, st)                                                   \
  do {                                                                       \
    int kb = (tt) << 6; const u16* g; int gk;                                \
    if (kb < ksplit) { g = a1; gk = kb; } else { g = a2; gk = kb - ksplit; } \
    const u16* src = g + (size_t)(m0 + (st) * 16 + stR) * lda + gk + stS;    \
    gload_lds16(src, (buf) + (st) * 1024);                                   \
    gload_lds16(src + (size_t)8 * lda, (buf) + (st) * 1024 + 512);           \
  } while (0)
#define STG_B(tt, buf, st)                                                   \
  do {                                                                       \
    int kb = (tt) << 6;                                                      \
    const u16* src = bw + (size_t)(n0 + (st) * 16 + stR) * ldb + kb + stS;   \
    gload_lds16(src, (buf) + (st) * 1024);                                   \
    gload_lds16(src + (size_t)8 * ldb, (buf) + (st) * 1024 + 512);           \
  } while (0)
#define BARR                                                                 \
  do {                                                                       \
    __builtin_amdgcn_s_barrier();                                            \
    asm volatile("s_waitcnt lgkmcnt(0)" ::: "memory");                       \
    __builtin_amdgcn_sched_barrier(0);                                       \
  } while (0)
#define MM(mb_)                                                              \
  do {                                                                       \
    __builtin_amdgcn_s_setprio(1);                                           \
    _Pragma("unroll") for (int mh = 0; mh < 2; ++mh)                         \
    _Pragma("unroll") for (int n = 0; n < 4; ++n) {                          \
      acc[(mb_) + mh][n] = __builtin_amdgcn_mfma_f32_16x16x32_bf16(          \
          afr[mh][0], bfr[n][0], acc[(mb_) + mh][n], 0, 0, 0);               \
      acc[(mb_) + mh][n] = __builtin_amdgcn_mfma_f32_16x16x32_bf16(          \
          afr[mh][1], bfr[n][1], acc[(mb_) + mh][n], 0, 0, 0);               \
    }                                                                        \
    __builtin_amdgcn_s_setprio(0);                                           \
  } while (0)
#define LDA2(Ab, mb_)                                                        \
  do {                                                                       \
    afr[0][0] = *(const bf16x8*)((Ab) + (wm * 8 + (mb_)) * 1024 + fo0);      \
    afr[0][1] = *(const bf16x8*)((Ab) + (wm * 8 + (mb_)) * 1024 + fo1);      \
    afr[1][0] = *(const bf16x8*)((Ab) + (wm * 8 + (mb_) + 1) * 1024 + fo0);  \
    afr[1][1] = *(const bf16x8*)((Ab) + (wm * 8 + (mb_) + 1) * 1024 + fo1);  \
  } while (0)

#define TILE(t, Ab, Bb, An, Bn)                                              \
  do {                                                                       \
    const bool stg = (t) + 1 < NT;                                           \
    bf16x8 bfr[4][2], afr[2][2];                                             \
    _Pragma("unroll") for (int n = 0; n < 4; ++n) {                          \
      bfr[n][0] = *(const bf16x8*)((Bb) + (wn * 4 + n) * 1024 + fo0);        \
      bfr[n][1] = *(const bf16x8*)((Bb) + (wn * 4 + n) * 1024 + fo1);        \
    }                                                                        \
    LDA2(Ab, 0);                                                             \
    if (stg) STG_B((t) + 1, Bn, wid);                                        \
    BARR; MM(0);                                                             \
    LDA2(Ab, 2);                                                             \
    if (stg) {                                                               \
      STG_B((t) + 1, Bn, 8 + wid);                                           \
      asm volatile("s_waitcnt vmcnt(4)" ::: "memory");                       \
    } else {                                                                 \
      asm volatile("s_waitcnt vmcnt(0)" ::: "memory");                       \
    }                                                                        \
    BARR; MM(2);                                                             \
    LDA2(Ab, 4);                                                             \
    if (stg) STG_A((t) + 1, An, a1w);                                        \
    BARR; MM(4);                                                             \
    LDA2(Ab, 6);                                                             \
    if (stg) {                                                               \
      STG_A((t) + 1, An, a2w);                                               \
      asm volatile("s_waitcnt vmcnt(2)" ::: "memory");                       \
    }                                                                        \
    BARR; MM(6);                                                             \
  } while (0)

  STG_A(0, A0, wid); STG_A(0, A0, wid + 8);
  STG_B(0, B0, wid); STG_B(0, B0, wid + 8);
  asm volatile("s_waitcnt vmcnt(0)" ::: "memory");
  __builtin_amdgcn_s_barrier();

  for (int t = 0; t < NT; t += 2) {
    TILE(t, A0, B0, A1s, B1s);
    if (t + 1 < NT) TILE(t + 1, A1s, B1s, A0, B0);
  }
#undef TILE
#undef LDA2
#undef MM
#undef BARR
#undef STG_A
#undef STG_B

  const int crow = (lane >> 4) * 4;
  const int ccol = lane & 15;

  if (POOL) {
    // fused masked pooling: per-column sums of tanh(acc + bias) over live rows
    const int b = m0 >> 10;
    const int lenv = lenb[b];
    const int qbase = (m0 & 1023) + wm * 128 + crow;
    float csum[4] = {0.f, 0.f, 0.f, 0.f};
#pragma unroll
    for (int j = 0; j < 4; ++j) {
      int c = n0 + wn * 64 + j * 16 + ccol;
      float bb = bias[c];
#pragma unroll
      for (int i = 0; i < 8; ++i) {
#pragma unroll
        for (int t = 0; t < 4; ++t) {
          int q = qbase + i * 16 + t;
          float v = tanh_fast(acc[i][j][t] + bb);
          csum[j] += (q < lenv) ? v : 0.f;
        }
      }
    }
    float* red = (float*)A0;  // [wm][wn][64] = 2 KB (LDS reuse after loop)
#pragma unroll
    for (int j = 0; j < 4; ++j) {
      float cs = csum[j];
      cs += __shfl_xor(cs, 16);
      cs += __shfl_xor(cs, 32);
      if (lane < 16) red[(wm * 4 + wn) * 64 + j * 16 + lane] = cs;
    }
    __syncthreads();
    if (tid < 256) {
      int wnn = tid >> 6, cl = tid & 63;
      float v = red[(0 * 4 + wnn) * 64 + cl] + red[(1 * 4 + wnn) * 64 + cl];
      pf[(size_t)mb * 1024 + n0 + wnn * 64 + cl] = v;
    }
    return;
  }

#pragma unroll
  for (int i = 0; i < 8; ++i) {
#pragma unroll
    for (int j = 0; j < 4; ++j) {
      int r0 = m0 + wm * 128 + i * 16 + crow;
      int c = n0 + wn * 64 + j * 16 + ccol;
      float bb = HAS_BIAS ? bias[(size_t)bz * sBias + c] : 0.f;
#pragma unroll
      for (int t = 0; t < 4; ++t) {
        float v = acc[i][j][t] + bb;
        if (DO_TANH) v = tanh_fast(v);
        size_t idx = (size_t)bz * sC + (size_t)(r0 + t) * ldc + c;
        if (OUTT == 0) {
          ((float*)Cout)[idx] = v;
        } else if (OUTT == 1) {
          ((u16*)Cout)[idx] = f2bf(v);
        } else {
          __half hv = __float2half(v);
          ((u16*)Cout)[idx] = __half_as_ushort(hv);
        }
      }
    }
  }
}

// -------- softmax over keys (mask); logits fp16 already include v-bias ------
// Reads only k < len (dead keys masked anyway); writes only k < ceil64(len)
// (mix truncates K there; [len, Keff) written as exact zeros).
__global__ __launch_bounds__(256) void softmax_rows(const u16* __restrict__ logits,
                                                    const int* __restrict__ amask,
                                                    u16* __restrict__ P,
                                                    const int* __restrict__ lenb) {
  const int row = blockIdx.x;  // blocal*L + q
  const int b = row >> 10;
  const int q = row & 1023;
  const int len = lenb[b];
  if (q >= len) return;  // dead query row: P never read downstream
  const int keff = (len + 63) & ~63;
  const u16* lg = logits + (size_t)row * LSEQ;
  u16* prow = P + (size_t)row * LSEQ;
  const int tid = threadIdx.x;
  const bool live = (tid * 4) < len;

  float x[4];
  int mk[4] = {0, 0, 0, 0};
  if (live) {
    ushort4 lraw = ((const ushort4*)lg)[tid];
    int4 mk4 = ((const int4*)(amask + (b << 10)))[tid];
    mk[0] = mk4.x; mk[1] = mk4.y; mk[2] = mk4.z; mk[3] = mk4.w;
    x[0] = __half2float(__ushort_as_half(lraw.x));
    x[1] = __half2float(__ushort_as_half(lraw.y));
    x[2] = __half2float(__ushort_as_half(lraw.z));
    x[3] = __half2float(__ushort_as_half(lraw.w));
  }

  float vmax = -3.0e38f;
#pragma unroll
  for (int i = 0; i < 4; ++i) {
    if (!mk[i]) x[i] = -3.0e38f;
    vmax = fmaxf(vmax, x[i]);
  }
#pragma unroll
  for (int o = 32; o; o >>= 1) vmax = fmaxf(vmax, __shfl_xor(vmax, o));
  __shared__ float sred[4];
  if ((tid & 63) == 0) sred[tid >> 6] = vmax;
  __syncthreads();
  vmax = fmaxf(fmaxf(sred[0], sred[1]), fmaxf(sred[2], sred[3]));
  float s = 0.f, e[4];
#pragma unroll
  for (int i = 0; i < 4; ++i) {
    e[i] = mk[i] ? __expf(x[i] - vmax) : 0.f;
    s += e[i];
  }
#pragma unroll
  for (int o = 32; o; o >>= 1) s += __shfl_xor(s, o);
  __shared__ float ssum[4];
  if ((tid & 63) == 0) ssum[tid >> 6] = s;
  __syncthreads();
  s = (ssum[0] + ssum[1]) + (ssum[2] + ssum[3]);
  float inv = 1.f / s;
  if ((tid * 4) < keff) {
    ushort4 o4;
    o4.x = f2bf(e[0] * inv);
    o4.y = f2bf(e[1] * inv);
    o4.z = f2bf(e[2] * inv);
    o4.w = f2bf(e[3] * inv);
    ((ushort4*)prow)[tid] = o4;
  }
}

// ------- final pooling: sum live pf chunks, divide by length -------
__global__ __launch_bounds__(256) void pool_final(const float* __restrict__ pf,
                                                  const int* __restrict__ lenb,
                                                  float* __restrict__ out) {
  int idx = blockIdx.x * 256 + threadIdx.x;  // b*D + d
  int b = idx >> 10;
  int d = idx & 1023;
  int len = lenb[b];
  float s = 0.f;
#pragma unroll
  for (int qc = 0; qc < 4; ++qc)
    if (qc * 256 < len) s += pf[(size_t)(b * 4 + qc) * 1024 + d];
  out[idx] = s / (float)len;
}

extern "C" void kernel_launch(void* const* d_in, const int* in_sizes, int n_in,
                              void* d_out, int out_size, void* d_ws, size_t ws_size,
                              hipStream_t stream) {
  const float* output = (const float*)d_in[0];
  const float* context = (const float*)d_in[1];
  const int* amask = (const int*)d_in[2];
  const float* Wo = (const float*)d_in[3];
  const float* bo = (const float*)d_in[4];
  const float* Wc = (const float*)d_in[5];
  const float* Wb = (const float*)d_in[7];
  const float* Wv = (const float*)d_in[10];
  const float* Wf = (const float*)d_in[12];
  const float* bfb = (const float*)d_in[13];
  float* out = (float*)d_out;
  (void)n_in; (void)in_sizes; (void)out_size;

  const size_t LD2 = (size_t)LSEQ * DDIM * 2;
  const size_t fixed_b = (size_t)24 * (1 << 20);
  const size_t per_b = 4 * LD2 + (size_t)LSEQ * LSEQ * 2 + 80 * LSEQ + 4096;
  int G = 1;
  for (int g : {32, 16, 8, 4, 2, 1}) {
    if (fixed_b + (size_t)g * per_b <= ws_size) { G = g; break; }
  }
  const int NG = BATCH / G;
  const int VN = G * LSEQ;

  char* ws = (char*)d_ws;
  size_t off = 0;
  auto alloc = [&](size_t bytes) {
    char* p = ws + off;
    off += (bytes + 255) & ~(size_t)255;
    return p;
  };
  const size_t W2 = (size_t)DDIM * DDIM * 2;
  u16* wb_bf = (u16*)alloc(W2);
  u16* wf_bf = (u16*)alloc(2 * W2);
  u16* woT_bf = (u16*)alloc(W2);
  u16* wcT_bf = (u16*)alloc(W2);
  u16* wboT_bf = (u16*)alloc(W2);
  u16* mt_bf = (u16*)alloc(W2);
  float* bbo = (float*)alloc(DDIM * 4);
  float* wv2 = (float*)alloc(DDIM * 4);
  int* lenb = (int*)alloc(BATCH * 4);
  float* pf = (float*)alloc((size_t)BATCH * 4 * DDIM * 4);  // [B*4][1024]
  u16* out_g = (u16*)alloc((size_t)G * LD2);
  u16* ctx_g = (u16*)alloc((size_t)G * LD2);
  u16* ctxT_g = (u16*)alloc((size_t)G * LD2);
  u16* y_g = (u16*)alloc((size_t)G * LD2);
  u16* logits = (u16*)alloc((size_t)G * LSEQ * LSEQ * 2);  // fp16
  float* vbuf = (float*)alloc((size_t)VN * 4);
  float* vpart = (float*)alloc((size_t)16 * VN * 4);

  dim3 blk(256), blk8(512);
  const long long M1 = (long long)LSEQ * DDIM;
  const int BIG = 1 << 30;

  // ---- lengths + weight precompute ----
  len_kernel<<<dim3(BATCH), blk, 0, stream>>>(amask, lenb);
  cvt_kernel<<<dim3(1024), blk, 0, stream>>>(Wb, wb_bf, DDIM * DDIM / 4);
  cvt_kernel<<<dim3(2048), blk, 0, stream>>>(Wf, wf_bf, DDIM * 2 * DDIM / 4);
  transpose_cv<<<dim3(16, 16, 1), blk, 0, stream>>>(Wo, woT_bf, nullptr, nullptr, nullptr, 0);
  transpose_cv<<<dim3(16, 16, 1), blk, 0, stream>>>(Wc, wcT_bf, nullptr, nullptr, nullptr, 0);
  rowdot_kernel<<<dim3(1024), blk, 0, stream>>>(Wb, bo, bbo);
  w2_kernel<<<dim3(4), blk, 0, stream>>>(Wv, bbo, Wc, wv2);
  gemm_nt<0, 0, 0, 0><<<dim3(64), blk, 0, stream>>>(
      woT_bf, woT_bf, BIG, wb_bf, nullptr, wboT_bf,
      1024, 1024, 1024, 1024, 0, 0, 0, 8, 8, 1);
  gemm_nt<0, 0, 0, 0><<<dim3(64), blk, 0, stream>>>(
      wcT_bf, wcT_bf, BIG, wboT_bf, nullptr, mt_bf,
      1024, 1024, 1024, 1024, 0, 0, 0, 8, 8, 1);

  for (int grp = 0; grp < NG; ++grp) {
    const int gb = grp * G;
    const float* outp = output + (size_t)gb * LSEQ * DDIM;
    const float* ctxp = context + (size_t)gb * LSEQ * DDIM;
    const int* amp = amask + (size_t)gb * LSEQ;
    const int* lnp = lenb + gb;
    const int n4 = G * LSEQ * DDIM / 4;

    cvt_kernel<<<dim3(n4 / 256), blk, 0, stream>>>(outp, out_g, n4);
    // transpose + bf16 copy + fused partial v-dot
    transpose_cv<<<dim3(16, 16, G), blk, 0, stream>>>(ctxp, ctxT_g, ctx_g, wv2, vpart, VN);
    vred_kernel<<<dim3(VN / 256), blk, 0, stream>>>(vpart, vbuf, VN);

    // y = output @ M   [dense, bf16 out; skip dead q-blocks]
    gemm8p<1, 0, 0, 0, 1, 0><<<dim3(G * 16), blk8, 0, stream>>>(
        out_g, out_g, BIG, mt_bf, nullptr, 0, y_g,
        1024, 1024, 1024, 1024, 0, 0, 0, G * 4, 4, 1, lnp, nullptr);
    // logits[b] = y[b] @ ctx[b]^T + v[k]  [fp16 out; skip dead m,n blocks]
    gemm8p<2, 1, 0, 1, 3, 0><<<dim3(G * 16), blk8, 0, stream>>>(
        y_g, y_g, BIG, ctx_g, vbuf, 1024, logits,
        1024, 1024, 1024, 1024, M1, M1, M1, 4, 4, G, lnp, nullptr);
    // P = softmax(logits + mask) -> bf16 into y_g (skip dead rows)
    softmax_rows<<<dim3(G * LSEQ), blk, 0, stream>>>(logits, amp, y_g, lnp);
    // mix[b] = P[b] @ ctxT[b]^T -> bf16 into ctx_g (skip dead m; truncate K)
    gemm8p<1, 0, 0, 1, 5, 0><<<dim3(G * 16), blk8, 0, stream>>>(
        y_g, y_g, BIG, ctxT_g, nullptr, 0, ctx_g,
        1024, 1024, 1024, 1024, M1, M1, M1, 4, 4, G, lnp, nullptr);
    // fc + fused masked pooling: tanh([out, mix] @ Wf^T + bf) summed -> pf
    gemm8p<1, 1, 1, 0, 1, 1><<<dim3(G * 16), blk8, 0, stream>>>(
        out_g, ctx_g, 1024, wf_bf, bfb, 0, nullptr,
        2048, 1024, 2048, 1024, 0, 0, 0, G * 4, 4, 1, lnp,
        pf + (size_t)gb * 4 * DDIM);
  }
  pool_final<<<dim3(128), blk, 0, stream>>>(pf, lenb, out);
}

// Round 13
// 539.705 us; speedup vs baseline: 1.1313x; 1.0698x over previous
//
#include <hip/hip_runtime.h>
#include <hip/hip_fp16.h>
#include <cstdint>
#include <initializer_list>

#define BATCH 32
#define LSEQ 1024
#define DDIM 1024

typedef unsigned short u16;
typedef unsigned int u32;
typedef __bf16 bf16x8 __attribute__((ext_vector_type(8)));
typedef float f32x4 __attribute__((ext_vector_type(4)));

__device__ __forceinline__ u16 f2bf(float f) {
  u32 u = __float_as_uint(f);
  u32 r = (u + 0x7FFFu + ((u >> 16) & 1u)) >> 16;
  return (u16)r;
}
__device__ __forceinline__ float bf2f(u16 h) {
  return __uint_as_float(((u32)h) << 16);
}
__device__ __forceinline__ float tanh_fast(float x) {
  float xx = fminf(fmaxf(x, -15.f), 15.f);
  float t = __expf(2.f * xx);
  return (t - 1.f) / (t + 1.f);
}

__device__ __forceinline__ void gload_lds16(const void* g, void* l) {
  __builtin_amdgcn_global_load_lds(
      (__attribute__((address_space(1))) void*)(uintptr_t)g,
      (__attribute__((address_space(3))) void*)(u32)(uintptr_t)l,
      16, 0, 0);
}

// ---------------- per-batch valid length from attention mask ----------------
__global__ __launch_bounds__(256) void len_kernel(const int* __restrict__ amask,
                                                  int* __restrict__ lenb) {
  int b = blockIdx.x;
  int4 m = ((const int4*)(amask + (size_t)b * LSEQ))[threadIdx.x];
  int s = m.x + m.y + m.z + m.w;
#pragma unroll
  for (int o = 32; o; o >>= 1) s += __shfl_xor(s, o);
  __shared__ int r[4];
  if ((threadIdx.x & 63) == 0) r[threadIdx.x >> 6] = s;
  __syncthreads();
  if (threadIdx.x == 0) lenb[b] = (r[0] + r[1]) + (r[2] + r[3]);
}

// ---------------- fp32 -> bf16 convert (vectorized x4; weights only) --------
__global__ __launch_bounds__(256) void cvt_kernel(const float* __restrict__ in,
                                                  u16* __restrict__ out, int n4) {
  int i = blockIdx.x * 256 + threadIdx.x;
  if (i >= n4) return;
  float4 f = ((const float4*)in)[i];
  ushort4 o;
  o.x = f2bf(f.x); o.y = f2bf(f.y); o.z = f2bf(f.z); o.w = f2bf(f.w);
  ((ushort4*)out)[i] = o;
}

// ------- transpose+convert [L,D]f32 -> [D,L]bf16 (weights only) -------------
__global__ __launch_bounds__(256) void transpose_cv(const float* __restrict__ in,
                                                    u16* __restrict__ outT) {
  __shared__ u16 tile[64][65];
  int k0 = blockIdx.x * 64;
  int d0 = blockIdx.y * 64;
  int tx = threadIdx.x & 63;
  int ty = threadIdx.x >> 6;
#pragma unroll
  for (int r = ty; r < 64; r += 4)
    tile[r][tx] = f2bf(in[(size_t)(k0 + r) * DDIM + d0 + tx]);
  __syncthreads();
#pragma unroll
  for (int r = ty; r < 64; r += 4)
    outT[(size_t)(d0 + r) * LSEQ + k0 + tx] = tile[tx][r];
}

// ---- fused prep: out cvt + ctx cvt + ctx transpose + partial v-dot, all
// masked at ceil256(len) (rows/cols beyond are never read downstream) ----
__global__ __launch_bounds__(256) void prep_kernel(
    const float* __restrict__ outp, const float* __restrict__ ctxp,
    u16* __restrict__ out_g, u16* __restrict__ ctx_g, u16* __restrict__ ctxT_g,
    const float* __restrict__ wv2, float* __restrict__ vpart, int vn,
    const int* __restrict__ lenb) {
  const int b = blockIdx.z;
  int keff = (lenb[b] + 255) & ~255;
  if (keff > LSEQ) keff = LSEQ;
  const int k0 = blockIdx.x * 64;  // L index (ctx key row / output q row)
  if (k0 >= keff) return;
  const int d0 = blockIdx.y * 64;  // D index
  __shared__ u16 tile[64][65];
  const size_t boff = (size_t)b * (LSEQ * DDIM);
  const int tx = threadIdx.x & 63;
  const int ty = threadIdx.x >> 6;
  const float wv = wv2[d0 + tx];
#pragma unroll
  for (int r = ty; r < 64; r += 4) {
    size_t idx = boff + (size_t)(k0 + r) * DDIM + d0 + tx;
    float f = ctxp[idx];
    u16 h = f2bf(f);
    tile[r][tx] = h;
    ctx_g[idx] = h;
    out_g[idx] = f2bf(outp[idx]);
    float p = f * wv;
#pragma unroll
    for (int o = 32; o; o >>= 1) p += __shfl_xor(p, o);
    if (tx == 0) vpart[(size_t)blockIdx.y * vn + b * LSEQ + k0 + r] = p;
  }
  __syncthreads();
#pragma unroll
  for (int r = ty; r < 64; r += 4)
    ctxT_g[boff + (size_t)(d0 + r) * LSEQ + k0 + tx] = tile[tx][r];
}

// ---- vbuf[i] = sum_s vpart[s][i] ----
__global__ __launch_bounds__(256) void vred_kernel(const float* __restrict__ vpart,
                                                   float* __restrict__ vbuf, int vn) {
  int i = blockIdx.x * 256 + threadIdx.x;
  if (i >= vn) return;
  float s = 0.f;
#pragma unroll
  for (int p = 0; p < 16; ++p) s += vpart[(size_t)p * vn + i];
  vbuf[i] = s;
}

// ---------------- out[row] = x[row,:] dot w[:]  (fp32) ----------------
__global__ __launch_bounds__(256) void rowdot_kernel(const float* __restrict__ x,
                                                     const float* __restrict__ w,
                                                     float* __restrict__ out) {
  int row = blockIdx.x;
  const float* p = x + (size_t)row * DDIM;
  int tid = threadIdx.x;
  float4 a = ((const float4*)p)[tid];
  float4 ww = ((const float4*)w)[tid];
  float s = a.x * ww.x + a.y * ww.y + a.z * ww.z + a.w * ww.w;
#pragma unroll
  for (int o = 32; o; o >>= 1) s += __shfl_xor(s, o);
  __shared__ float r[4];
  if ((tid & 63) == 0) r[tid >> 6] = s;
  __syncthreads();
  if (tid == 0) out[row] = (r[0] + r[1]) + (r[2] + r[3]);
}

// ---- wv2[d] = Wv[d] + sum_e bbo[e] * Wc[e,d] ----
__global__ __launch_bounds__(256) void w2_kernel(const float* __restrict__ Wv,
                                                 const float* __restrict__ bbo,
                                                 const float* __restrict__ Wc,
                                                 float* __restrict__ wv2) {
  int d = blockIdx.x * 256 + threadIdx.x;
  float s = Wv[d];
  for (int e = 0; e < DDIM; ++e) s += bbo[e] * Wc[(size_t)e * DDIM + d];
  wv2[d] = s;
}

// ============ small 128x128 2-phase GEMM (weight precompute only) ===========
template <int OUT_F32, int HAS_BIAS, int DO_TANH, int ZBATCH>
__global__ __launch_bounds__(256) void gemm_nt(
    const u16* __restrict__ A1, const u16* __restrict__ A2, int ksplit,
    const u16* __restrict__ Bw, const float* __restrict__ bias,
    void* __restrict__ Cout, int K, int lda, int ldb, int ldc,
    long long sA, long long sB, long long sC, int nm, int nn, int nz) {
  __shared__ u16 As[4096];
  __shared__ u16 Bs[4096];

  const int id = blockIdx.x;
  int bz, mb, nb;
  if (ZBATCH) {
    if ((nz & 7) == 0) {
      int x = id & 7; int j = id >> 3; int pb = nm * nn;
      bz = x + 8 * (j / pb);
      int in_ = j % pb; nb = in_ % nn; mb = in_ / nn;
    } else { bz = id % nz; int t = id / nz; nb = t % nn; mb = t / nn; }
  } else {
    bz = 0;
    if ((nm & 7) == 0) {
      int mg = id & 7; int t = id >> 3; int nmg = nm >> 3;
      nb = t % nn; mb = mg * nmg + t / nn;
    } else { nb = id % nn; mb = id / nn; }
  }

  const int tid = threadIdx.x;
  const int lane = tid & 63;
  const int wid = tid >> 6;
  const int wm = wid >> 1;
  const int wn = wid & 1;
  const int m0 = mb * 128;
  const int n0 = nb * 128;

  const u16* a1 = A1 + (size_t)bz * sA;
  const u16* a2 = A2 + (size_t)bz * sA;
  const u16* bw = Bw + (size_t)bz * sB;

  const int srow = wid * 16 + (lane >> 2);
  const int skof = (lane & 3) * 8;

  f32x4 acc[4][4] = {};

  for (int k0 = 0; k0 < K; k0 += 32) {
    const u16* ab; int kk;
    if (k0 < ksplit) { ab = a1; kk = k0; } else { ab = a2; kk = k0 - ksplit; }
    const u16* asrc = ab + (size_t)(m0 + srow) * lda + kk + skof;
    const u16* bsrc = bw + (size_t)(n0 + srow) * ldb + k0 + skof;
    gload_lds16(asrc, &As[wid * 512]);
    gload_lds16(asrc + (size_t)64 * lda, &As[2048 + wid * 512]);
    gload_lds16(bsrc, &Bs[wid * 512]);
    gload_lds16(bsrc + (size_t)64 * ldb, &Bs[2048 + wid * 512]);
    __syncthreads();

    bf16x8 af[4], bfv[4];
#pragma unroll
    for (int i = 0; i < 4; ++i) {
      af[i] = *(const bf16x8*)&As[(wm * 64 + i * 16 + (lane & 15)) * 32 + (lane >> 4) * 8];
      bfv[i] = *(const bf16x8*)&Bs[(wn * 64 + i * 16 + (lane & 15)) * 32 + (lane >> 4) * 8];
    }
#pragma unroll
    for (int i = 0; i < 4; ++i)
#pragma unroll
      for (int j = 0; j < 4; ++j)
        acc[i][j] = __builtin_amdgcn_mfma_f32_16x16x32_bf16(af[i], bfv[j], acc[i][j], 0, 0, 0);
    __syncthreads();
  }

  const int crow = (lane >> 4) * 4;
  const int ccol = lane & 15;
#pragma unroll
  for (int i = 0; i < 4; ++i) {
#pragma unroll
    for (int j = 0; j < 4; ++j) {
      int r0 = m0 + wm * 64 + i * 16 + crow;
      int c = n0 + wn * 64 + j * 16 + ccol;
      float bb = HAS_BIAS ? bias[c] : 0.f;
#pragma unroll
      for (int t = 0; t < 4; ++t) {
        float v = acc[i][j][t] + bb;
        if (DO_TANH) v = tanh_fast(v);
        size_t idx = (size_t)bz * sC + (size_t)(r0 + t) * ldc + c;
        if (OUT_F32) ((float*)Cout)[idx] = v;
        else ((u16*)Cout)[idx] = f2bf(v);
      }
    }
  }
}

// ======= 256x256 8-phase GEMM (round-8 schedule: per-phase barrier,
// counted vmcnt(4)/vmcnt(2), st swizzle). MASK bits: 1=skip dead m,
// 2=skip dead n, 4=truncate K. OUTT: 0=f32, 1=bf16, 2=f16.
// POOL=1: fused masked pooling epilogue (tanh + per-column sums -> pf),
// no C write. bias indexed bias[bz*sBias + c].
template <int OUTT, int HAS_BIAS, int DO_TANH, int ZBATCH, int MASK, int POOL>
__global__ __launch_bounds__(512, 1) void gemm8p(
    const u16* __restrict__ A1, const u16* __restrict__ A2, int ksplit,
    const u16* __restrict__ Bw, const float* __restrict__ bias, long long sBias,
    void* __restrict__ Cout, int K, int lda, int ldb, int ldc,
    long long sA, long long sB, long long sC, int nm, int nn, int nz,
    const int* __restrict__ lenb, float* __restrict__ pf) {
  __shared__ __align__(16) u16 A0[16384];
  __shared__ __align__(16) u16 A1s[16384];
  __shared__ __align__(16) u16 B0[16384];
  __shared__ __align__(16) u16 B1s[16384];

  const int id = blockIdx.x;
  int bz, mb, nb;
  if (ZBATCH) {
    if ((nz & 7) == 0) {
      int x = id & 7; int j = id >> 3; int pb = nm * nn;
      bz = x + 8 * (j / pb);
      int in_ = j % pb; nb = in_ % nn; mb = in_ / nn;
    } else { bz = id % nz; int t = id / nz; nb = t % nn; mb = t / nn; }
  } else {
    bz = 0;
    if ((nm & 7) == 0) {
      int mg = id & 7; int t = id >> 3; int nmg = nm >> 3;
      nb = t % nn; mb = mg * nmg + t / nn;
    } else { nb = id % nn; mb = id / nn; }
  }

  const int m0 = mb * 256;
  const int n0 = nb * 256;

  int Keff = K;
  if (MASK) {
    if (MASK & 1) {
      int lb = ZBATCH ? bz : (m0 >> 10);
      int lm = ZBATCH ? m0 : (m0 & 1023);
      if (lm >= lenb[lb]) return;
    }
    if (MASK & 2) {
      if (n0 >= lenb[bz]) return;
    }
    if (MASK & 4) {
      Keff = (lenb[bz] + 63) & ~63;
    }
  }
  const int NT = Keff >> 6;  // K-tiles of 64

  const int tid = threadIdx.x;
  const int lane = tid & 63;
  const int wid = tid >> 6;  // 0..7
  const int wm = wid >> 2;   // 0..1 : 128-row half
  const int wn = wid & 3;    // 0..3 : 64-col quarter

  const u16* a1 = A1 + (size_t)bz * sA;
  const u16* a2 = A2 + (size_t)bz * sA;
  const u16* bw = Bw + (size_t)bz * sB;

  const int stR = lane >> 3;
  const int stS = ((lane & 7) ^ (lane >> 3)) * 8;  // u16 units
  const int a1w = (wid < 4) ? wid : 4 + wid;
  const int a2w = (wid < 4) ? 4 + wid : 8 + wid;

  const int frr = lane & 15;
  const int fo0 = frr * 64 + (((lane >> 4)) ^ (frr & 7)) * 8;
  const int fo1 = frr * 64 + ((4 + (lane >> 4)) ^ (frr & 7)) * 8;

  f32x4 acc[8][4] = {};

#define STG_A(tt, buf, st)                                                   \
  do {                                                                       \
    int kb = (tt) << 6; const u16* g; int gk;                                \
    if (kb < ksplit) { g = a1; gk = kb; } else { g = a2; gk = kb - ksplit; } \
    const u16* src = g + (size_t)(m0 + (st) * 16 + stR) * lda + gk + stS;    \
    gload_lds16(src, (buf) + (st) * 1024);                                   \
    gload_lds16(src + (size_t)8 * lda, (buf) + (st) * 1024 + 512);           \
  } while (0)
#define STG_B(tt, buf, st)                                                   \
  do {                                                                       \
    int kb = (tt) << 6;                                                      \
    const u16* src = bw + (size_t)(n0 + (st) * 16 + stR) * ldb + kb + stS;   \
    gload_lds16(src, (buf) + (st) * 1024);                                   \
    gload_lds16(src + (size_t)8 * ldb, (buf) + (st) * 1024 + 512);           \
  } while (0)
#define BARR                                                                 \
  do {                                                                       \
    __builtin_amdgcn_s_barrier();                                            \
    asm volatile("s_waitcnt lgkmcnt(0)" ::: "memory");                       \
    __builtin_amdgcn_sched_barrier(0);                                       \
  } while (0)
#define MM(mb_)                                                              \
  do {                                                                       \
    __builtin_amdgcn_s_setprio(1);                                           \
    _Pragma("unroll") for (int mh = 0; mh < 2; ++mh)                         \
    _Pragma("unroll") for (int n = 0; n < 4; ++n) {                          \
      acc[(mb_) + mh][n] = __builtin_amdgcn_mfma_f32_16x16x32_bf16(          \
          afr[mh][0], bfr[n][0], acc[(mb_) + mh][n], 0, 0, 0);               \
      acc[(mb_) + mh][n] = __builtin_amdgcn_mfma_f32_16x16x32_bf16(          \
          afr[mh][1], bfr[n][1], acc[(mb_) + mh][n], 0, 0, 0);               \
    }                                                                        \
    __builtin_amdgcn_s_setprio(0);                                           \
  } while (0)
#define LDA2(Ab, mb_)                                                        \
  do {                                                                       \
    afr[0][0] = *(const bf16x8*)((Ab) + (wm * 8 + (mb_)) * 1024 + fo0);      \
    afr[0][1] = *(const bf16x8*)((Ab) + (wm * 8 + (mb_)) * 1024 + fo1);      \
    afr[1][0] = *(const bf16x8*)((Ab) + (wm * 8 + (mb_) + 1) * 1024 + fo0);  \
    afr[1][1] = *(const bf16x8*)((Ab) + (wm * 8 + (mb_) + 1) * 1024 + fo1);  \
  } while (0)

#define TILE(t, Ab, Bb, An, Bn)                                              \
  do {                                                                       \
    const bool stg = (t) + 1 < NT;                                           \
    bf16x8 bfr[4][2], afr[2][2];                                             \
    _Pragma("unroll") for (int n = 0; n < 4; ++n) {                          \
      bfr[n][0] = *(const bf16x8*)((Bb) + (wn * 4 + n) * 1024 + fo0);        \
      bfr[n][1] = *(const bf16x8*)((Bb) + (wn * 4 + n) * 1024 + fo1);        \
    }                                                                        \
    LDA2(Ab, 0);                                                             \
    if (stg) STG_B((t) + 1, Bn, wid);                                        \
    BARR; MM(0);                                                             \
    LDA2(Ab, 2);                                                             \
    if (stg) {                                                               \
      STG_B((t) + 1, Bn, 8 + wid);                                           \
      asm volatile("s_waitcnt vmcnt(4)" ::: "memory");                       \
    } else {                                                                 \
      asm volatile("s_waitcnt vmcnt(0)" ::: "memory");                       \
    }                                                                        \
    BARR; MM(2);                                                             \
    LDA2(Ab, 4);                                                             \
    if (stg) STG_A((t) + 1, An, a1w);                                        \
    BARR; MM(4);                                                             \
    LDA2(Ab, 6);                                                             \
    if (stg) {                                                               \
      STG_A((t) + 1, An, a2w);                                               \
      asm volatile("s_waitcnt vmcnt(2)" ::: "memory");                       \
    }                                                                        \
    BARR; MM(6);                                                             \
  } while (0)

  STG_A(0, A0, wid); STG_A(0, A0, wid + 8);
  STG_B(0, B0, wid); STG_B(0, B0, wid + 8);
  asm volatile("s_waitcnt vmcnt(0)" ::: "memory");
  __builtin_amdgcn_s_barrier();

  for (int t = 0; t < NT; t += 2) {
    TILE(t, A0, B0, A1s, B1s);
    if (t + 1 < NT) TILE(t + 1, A1s, B1s, A0, B0);
  }
#undef TILE
#undef LDA2
#undef MM
#undef BARR
#undef STG_A
#undef STG_B

  const int crow = (lane >> 4) * 4;
  const int ccol = lane & 15;

  if (POOL) {
    // fused masked pooling: per-column sums of tanh(acc + bias) over live rows
    const int b = m0 >> 10;
    const int lenv = lenb[b];
    const int qbase = (m0 & 1023) + wm * 128 + crow;
    float csum[4] = {0.f, 0.f, 0.f, 0.f};
#pragma unroll
    for (int j = 0; j < 4; ++j) {
      int c = n0 + wn * 64 + j * 16 + ccol;
      float bb = bias[c];
#pragma unroll
      for (int i = 0; i < 8; ++i) {
#pragma unroll
        for (int t = 0; t < 4; ++t) {
          int q = qbase + i * 16 + t;
          float v = tanh_fast(acc[i][j][t] + bb);
          csum[j] += (q < lenv) ? v : 0.f;
        }
      }
    }
    float* red = (float*)A0;  // [wm][wn][64] = 2 KB (LDS reuse after loop)
#pragma unroll
    for (int j = 0; j < 4; ++j) {
      float cs = csum[j];
      cs += __shfl_xor(cs, 16);
      cs += __shfl_xor(cs, 32);
      if (lane < 16) red[(wm * 4 + wn) * 64 + j * 16 + lane] = cs;
    }
    __syncthreads();
    if (tid < 256) {
      int wnn = tid >> 6, cl = tid & 63;
      float v = red[(0 * 4 + wnn) * 64 + cl] + red[(1 * 4 + wnn) * 64 + cl];
      pf[(size_t)mb * 1024 + n0 + wnn * 64 + cl] = v;
    }
    return;
  }

#pragma unroll
  for (int i = 0; i < 8; ++i) {
#pragma unroll
    for (int j = 0; j < 4; ++j) {
      int r0 = m0 + wm * 128 + i * 16 + crow;
      int c = n0 + wn * 64 + j * 16 + ccol;
      float bb = HAS_BIAS ? bias[(size_t)bz * sBias + c] : 0.f;
#pragma unroll
      for (int t = 0; t < 4; ++t) {
        float v = acc[i][j][t] + bb;
        if (DO_TANH) v = tanh_fast(v);
        size_t idx = (size_t)bz * sC + (size_t)(r0 + t) * ldc + c;
        if (OUTT == 0) {
          ((float*)Cout)[idx] = v;
        } else if (OUTT == 1) {
          ((u16*)Cout)[idx] = f2bf(v);
        } else {
          __half hv = __float2half(v);
          ((u16*)Cout)[idx] = __half_as_ushort(hv);
        }
      }
    }
  }
}

// -------- softmax over keys (mask); logits fp16 already include v-bias ------
__global__ __launch_bounds__(256) void softmax_rows(const u16* __restrict__ logits,
                                                    const int* __restrict__ amask,
                                                    u16* __restrict__ P,
                                                    const int* __restrict__ lenb) {
  const int row = blockIdx.x;  // blocal*L + q
  const int b = row >> 10;
  const int q = row & 1023;
  const int len = lenb[b];
  if (q >= len) return;  // dead query row: P never read downstream
  const int keff = (len + 63) & ~63;
  const u16* lg = logits + (size_t)row * LSEQ;
  u16* prow = P + (size_t)row * LSEQ;
  const int tid = threadIdx.x;
  const bool live = (tid * 4) < len;

  float x[4];
  int mk[4] = {0, 0, 0, 0};
  if (live) {
    ushort4 lraw = ((const ushort4*)lg)[tid];
    int4 mk4 = ((const int4*)(amask + (b << 10)))[tid];
    mk[0] = mk4.x; mk[1] = mk4.y; mk[2] = mk4.z; mk[3] = mk4.w;
    x[0] = __half2float(__ushort_as_half(lraw.x));
    x[1] = __half2float(__ushort_as_half(lraw.y));
    x[2] = __half2float(__ushort_as_half(lraw.z));
    x[3] = __half2float(__ushort_as_half(lraw.w));
  }

  float vmax = -3.0e38f;
#pragma unroll
  for (int i = 0; i < 4; ++i) {
    if (!mk[i]) x[i] = -3.0e38f;
    vmax = fmaxf(vmax, x[i]);
  }
#pragma unroll
  for (int o = 32; o; o >>= 1) vmax = fmaxf(vmax, __shfl_xor(vmax, o));
  __shared__ float sred[4];
  if ((tid & 63) == 0) sred[tid >> 6] = vmax;
  __syncthreads();
  vmax = fmaxf(fmaxf(sred[0], sred[1]), fmaxf(sred[2], sred[3]));
  float s = 0.f, e[4];
#pragma unroll
  for (int i = 0; i < 4; ++i) {
    e[i] = mk[i] ? __expf(x[i] - vmax) : 0.f;
    s += e[i];
  }
#pragma unroll
  for (int o = 32; o; o >>= 1) s += __shfl_xor(s, o);
  __shared__ float ssum[4];
  if ((tid & 63) == 0) ssum[tid >> 6] = s;
  __syncthreads();
  s = (ssum[0] + ssum[1]) + (ssum[2] + ssum[3]);
  float inv = 1.f / s;
  if ((tid * 4) < keff) {
    ushort4 o4;
    o4.x = f2bf(e[0] * inv);
    o4.y = f2bf(e[1] * inv);
    o4.z = f2bf(e[2] * inv);
    o4.w = f2bf(e[3] * inv);
    ((ushort4*)prow)[tid] = o4;
  }
}

// ------- final pooling: sum live pf chunks, divide by length -------
__global__ __launch_bounds__(256) void pool_final(const float* __restrict__ pf,
                                                  const int* __restrict__ lenb,
                                                  float* __restrict__ out) {
  int idx = blockIdx.x * 256 + threadIdx.x;  // b*D + d
  int b = idx >> 10;
  int d = idx & 1023;
  int len = lenb[b];
  float s = 0.f;
#pragma unroll
  for (int qc = 0; qc < 4; ++qc)
    if (qc * 256 < len) s += pf[(size_t)(b * 4 + qc) * 1024 + d];
  out[idx] = s / (float)len;
}

extern "C" void kernel_launch(void* const* d_in, const int* in_sizes, int n_in,
                              void* d_out, int out_size, void* d_ws, size_t ws_size,
                              hipStream_t stream) {
  const float* output = (const float*)d_in[0];
  const float* context = (const float*)d_in[1];
  const int* amask = (const int*)d_in[2];
  const float* Wo = (const float*)d_in[3];
  const float* bo = (const float*)d_in[4];
  const float* Wc = (const float*)d_in[5];
  const float* Wb = (const float*)d_in[7];
  const float* Wv = (const float*)d_in[10];
  const float* Wf = (const float*)d_in[12];
  const float* bfb = (const float*)d_in[13];
  float* out = (float*)d_out;
  (void)n_in; (void)in_sizes; (void)out_size;

  const size_t LD2 = (size_t)LSEQ * DDIM * 2;
  const size_t fixed_b = (size_t)24 * (1 << 20);
  const size_t per_b = 4 * LD2 + (size_t)LSEQ * LSEQ * 2 + 80 * LSEQ + 4096;
  int G = 1;
  for (int g : {32, 16, 8, 4, 2, 1}) {
    if (fixed_b + (size_t)g * per_b <= ws_size) { G = g; break; }
  }
  const int NG = BATCH / G;
  const int VN = G * LSEQ;

  char* ws = (char*)d_ws;
  size_t off = 0;
  auto alloc = [&](size_t bytes) {
    char* p = ws + off;
    off += (bytes + 255) & ~(size_t)255;
    return p;
  };
  const size_t W2 = (size_t)DDIM * DDIM * 2;
  u16* wb_bf = (u16*)alloc(W2);
  u16* wf_bf = (u16*)alloc(2 * W2);
  u16* woT_bf = (u16*)alloc(W2);
  u16* wcT_bf = (u16*)alloc(W2);
  u16* wboT_bf = (u16*)alloc(W2);
  u16* mt_bf = (u16*)alloc(W2);
  float* bbo = (float*)alloc(DDIM * 4);
  float* wv2 = (float*)alloc(DDIM * 4);
  int* lenb = (int*)alloc(BATCH * 4);
  float* pf = (float*)alloc((size_t)BATCH * 4 * DDIM * 4);  // [B*4][1024]
  u16* out_g = (u16*)alloc((size_t)G * LD2);
  u16* ctx_g = (u16*)alloc((size_t)G * LD2);
  u16* ctxT_g = (u16*)alloc((size_t)G * LD2);
  u16* y_g = (u16*)alloc((size_t)G * LD2);
  u16* logits = (u16*)alloc((size_t)G * LSEQ * LSEQ * 2);  // fp16
  float* vbuf = (float*)alloc((size_t)VN * 4);
  float* vpart = (float*)alloc((size_t)16 * VN * 4);

  dim3 blk(256), blk8(512);
  const long long M1 = (long long)LSEQ * DDIM;
  const int BIG = 1 << 30;

  // ---- lengths + weight precompute ----
  len_kernel<<<dim3(BATCH), blk, 0, stream>>>(amask, lenb);
  cvt_kernel<<<dim3(1024), blk, 0, stream>>>(Wb, wb_bf, DDIM * DDIM / 4);
  cvt_kernel<<<dim3(2048), blk, 0, stream>>>(Wf, wf_bf, DDIM * 2 * DDIM / 4);
  transpose_cv<<<dim3(16, 16), blk, 0, stream>>>(Wo, woT_bf);
  transpose_cv<<<dim3(16, 16), blk, 0, stream>>>(Wc, wcT_bf);
  rowdot_kernel<<<dim3(1024), blk, 0, stream>>>(Wb, bo, bbo);
  w2_kernel<<<dim3(4), blk, 0, stream>>>(Wv, bbo, Wc, wv2);
  gemm_nt<0, 0, 0, 0><<<dim3(64), blk, 0, stream>>>(
      woT_bf, woT_bf, BIG, wb_bf, nullptr, wboT_bf,
      1024, 1024, 1024, 1024, 0, 0, 0, 8, 8, 1);
  gemm_nt<0, 0, 0, 0><<<dim3(64), blk, 0, stream>>>(
      wcT_bf, wcT_bf, BIG, wboT_bf, nullptr, mt_bf,
      1024, 1024, 1024, 1024, 0, 0, 0, 8, 8, 1);

  for (int grp = 0; grp < NG; ++grp) {
    const int gb = grp * G;
    const float* outp = output + (size_t)gb * LSEQ * DDIM;
    const float* ctxp = context + (size_t)gb * LSEQ * DDIM;
    const int* amp = amask + (size_t)gb * LSEQ;
    const int* lnp = lenb + gb;

    // fused prep: out cvt + ctx cvt + transpose + partial v-dot (masked)
    prep_kernel<<<dim3(16, 16, G), blk, 0, stream>>>(
        outp, ctxp, out_g, ctx_g, ctxT_g, wv2, vpart, VN, lnp);
    vred_kernel<<<dim3(VN / 256), blk, 0, stream>>>(vpart, vbuf, VN);

    // y = output @ M   [dense, bf16 out; skip dead q-blocks]
    gemm8p<1, 0, 0, 0, 1, 0><<<dim3(G * 16), blk8, 0, stream>>>(
        out_g, out_g, BIG, mt_bf, nullptr, 0, y_g,
        1024, 1024, 1024, 1024, 0, 0, 0, G * 4, 4, 1, lnp, nullptr);
    // logits[b] = y[b] @ ctx[b]^T + v[k]  [fp16 out; skip dead m,n blocks]
    gemm8p<2, 1, 0, 1, 3, 0><<<dim3(G * 16), blk8, 0, stream>>>(
        y_g, y_g, BIG, ctx_g, vbuf, 1024, logits,
        1024, 1024, 1024, 1024, M1, M1, M1, 4, 4, G, lnp, nullptr);
    // P = softmax(logits + mask) -> bf16 into y_g (skip dead rows)
    softmax_rows<<<dim3(G * LSEQ), blk, 0, stream>>>(logits, amp, y_g, lnp);
    // mix[b] = P[b] @ ctxT[b]^T -> bf16 into ctx_g (skip dead m; truncate K)
    gemm8p<1, 0, 0, 1, 5, 0><<<dim3(G * 16), blk8, 0, stream>>>(
        y_g, y_g, BIG, ctxT_g, nullptr, 0, ctx_g,
        1024, 1024, 1024, 1024, M1, M1, M1, 4, 4, G, lnp, nullptr);
    // fc + fused masked pooling: tanh([out, mix] @ Wf^T + bf) summed -> pf
    gemm8p<1, 1, 1, 0, 1, 1><<<dim3(G * 16), blk8, 0, stream>>>(
        out_g, ctx_g, 1024, wf_bf, bfb, 0, nullptr,
        2048, 1024, 2048, 1024, 0, 0, 0, G * 4, 4, 1, lnp,
        pf + (size_t)gb * 4 * DDIM);
  }
  pool_final<<<dim3(128), blk, 0, stream>>>(pf, lenb, out);
}

// Round 14
// 516.073 us; speedup vs baseline: 1.1831x; 1.0458x over previous
//
#include <hip/hip_runtime.h>
#include <hip/hip_fp16.h>
#include <cstdint>
#include <initializer_list>

#define BATCH 32
#define LSEQ 1024
#define DDIM 1024

typedef unsigned short u16;
typedef unsigned int u32;
typedef __bf16 bf16x8 __attribute__((ext_vector_type(8)));
typedef float f32x4 __attribute__((ext_vector_type(4)));

__device__ __forceinline__ u16 f2bf(float f) {
  u32 u = __float_as_uint(f);
  u32 r = (u + 0x7FFFu + ((u >> 16) & 1u)) >> 16;
  return (u16)r;
}
__device__ __forceinline__ float bf2f(u16 h) {
  return __uint_as_float(((u32)h) << 16);
}
__device__ __forceinline__ float tanh_fast(float x) {
  float xx = fminf(fmaxf(x, -15.f), 15.f);
  float t = __expf(2.f * xx);
  return (t - 1.f) / (t + 1.f);
}

__device__ __forceinline__ void gload_lds16(const void* g, void* l) {
  __builtin_amdgcn_global_load_lds(
      (__attribute__((address_space(1))) void*)(uintptr_t)g,
      (__attribute__((address_space(3))) void*)(u32)(uintptr_t)l,
      16, 0, 0);
}

// ---------------- per-batch valid length from attention mask ----------------
__global__ __launch_bounds__(256) void len_kernel(const int* __restrict__ amask,
                                                  int* __restrict__ lenb) {
  int b = blockIdx.x;
  int4 m = ((const int4*)(amask + (size_t)b * LSEQ))[threadIdx.x];
  int s = m.x + m.y + m.z + m.w;
#pragma unroll
  for (int o = 32; o; o >>= 1) s += __shfl_xor(s, o);
  __shared__ int r[4];
  if ((threadIdx.x & 63) == 0) r[threadIdx.x >> 6] = s;
  __syncthreads();
  if (threadIdx.x == 0) lenb[b] = (r[0] + r[1]) + (r[2] + r[3]);
}

// ---------------- fp32 -> bf16 convert (vectorized x4; weights only) --------
__global__ __launch_bounds__(256) void cvt_kernel(const float* __restrict__ in,
                                                  u16* __restrict__ out, int n4) {
  int i = blockIdx.x * 256 + threadIdx.x;
  if (i >= n4) return;
  float4 f = ((const float4*)in)[i];
  ushort4 o;
  o.x = f2bf(f.x); o.y = f2bf(f.y); o.z = f2bf(f.z); o.w = f2bf(f.w);
  ((ushort4*)out)[i] = o;
}

// --- dual transpose+convert [L,D]f32 -> [D,L]bf16 (two weight matrices) ----
__global__ __launch_bounds__(256) void transpose_w2(const float* __restrict__ A,
                                                    u16* __restrict__ AT,
                                                    const float* __restrict__ B,
                                                    u16* __restrict__ BT) {
  const float* src = blockIdx.z ? B : A;
  u16* dst = blockIdx.z ? BT : AT;
  __shared__ u16 tile[64][65];
  int k0 = blockIdx.x * 64;
  int d0 = blockIdx.y * 64;
  int tx = threadIdx.x & 63;
  int ty = threadIdx.x >> 6;
#pragma unroll
  for (int r = ty; r < 64; r += 4)
    tile[r][tx] = f2bf(src[(size_t)(k0 + r) * DDIM + d0 + tx]);
  __syncthreads();
#pragma unroll
  for (int r = ty; r < 64; r += 4)
    dst[(size_t)(d0 + r) * LSEQ + k0 + tx] = tile[tx][r];
}

// ---- fused prep: out cvt + ctx cvt + ctx transpose + partial v-dot, all
// masked at ceil256(len) (rows/cols beyond are never read downstream) ----
__global__ __launch_bounds__(256) void prep_kernel(
    const float* __restrict__ outp, const float* __restrict__ ctxp,
    u16* __restrict__ out_g, u16* __restrict__ ctx_g, u16* __restrict__ ctxT_g,
    const float* __restrict__ wv2, float* __restrict__ vpart, int vn,
    const int* __restrict__ lenb) {
  const int b = blockIdx.z;
  int keff = (lenb[b] + 255) & ~255;
  if (keff > LSEQ) keff = LSEQ;
  const int k0 = blockIdx.x * 64;  // L index (ctx key row / output q row)
  if (k0 >= keff) return;
  const int d0 = blockIdx.y * 64;  // D index
  __shared__ u16 tile[64][65];
  const size_t boff = (size_t)b * (LSEQ * DDIM);
  const int tx = threadIdx.x & 63;
  const int ty = threadIdx.x >> 6;
  const float wv = wv2[d0 + tx];
#pragma unroll
  for (int r = ty; r < 64; r += 4) {
    size_t idx = boff + (size_t)(k0 + r) * DDIM + d0 + tx;
    float f = ctxp[idx];
    u16 h = f2bf(f);
    tile[r][tx] = h;
    ctx_g[idx] = h;
    out_g[idx] = f2bf(outp[idx]);
    float p = f * wv;
#pragma unroll
    for (int o = 32; o; o >>= 1) p += __shfl_xor(p, o);
    if (tx == 0) vpart[(size_t)blockIdx.y * vn + b * LSEQ + k0 + r] = p;
  }
  __syncthreads();
#pragma unroll
  for (int r = ty; r < 64; r += 4)
    ctxT_g[boff + (size_t)(d0 + r) * LSEQ + k0 + tx] = tile[tx][r];
}

// ---- vbuf[i] = sum_s vpart[s][i] ----
__global__ __launch_bounds__(256) void vred_kernel(const float* __restrict__ vpart,
                                                   float* __restrict__ vbuf, int vn) {
  int i = blockIdx.x * 256 + threadIdx.x;
  if (i >= vn) return;
  float s = 0.f;
#pragma unroll
  for (int p = 0; p < 16; ++p) s += vpart[(size_t)p * vn + i];
  vbuf[i] = s;
}

// ---------------- out[row] = x[row,:] dot w[:]  (fp32) ----------------
__global__ __launch_bounds__(256) void rowdot_kernel(const float* __restrict__ x,
                                                     const float* __restrict__ w,
                                                     float* __restrict__ out) {
  int row = blockIdx.x;
  const float* p = x + (size_t)row * DDIM;
  int tid = threadIdx.x;
  float4 a = ((const float4*)p)[tid];
  float4 ww = ((const float4*)w)[tid];
  float s = a.x * ww.x + a.y * ww.y + a.z * ww.z + a.w * ww.w;
#pragma unroll
  for (int o = 32; o; o >>= 1) s += __shfl_xor(s, o);
  __shared__ float r[4];
  if ((tid & 63) == 0) r[tid >> 6] = s;
  __syncthreads();
  if (tid == 0) out[row] = (r[0] + r[1]) + (r[2] + r[3]);
}

// ---- w2 partials: w2p[eblk][d] = sum_{e in eblk} bbo[e]*Wc[e][d] ----
__global__ __launch_bounds__(256) void w2_part(const float* __restrict__ bbo,
                                               const float* __restrict__ Wc,
                                               float* __restrict__ w2p) {
  int d = blockIdx.x * 256 + threadIdx.x;
  int e0 = blockIdx.y * 64;
  float s = 0.f;
#pragma unroll 8
  for (int e = e0; e < e0 + 64; ++e) s += bbo[e] * Wc[(size_t)e * DDIM + d];
  w2p[(size_t)blockIdx.y * DDIM + d] = s;
}

// ---- wv2[d] = Wv[d] + sum_p w2p[p][d] ----
__global__ __launch_bounds__(256) void w2_red(const float* __restrict__ Wv,
                                              const float* __restrict__ w2p,
                                              float* __restrict__ wv2) {
  int d = blockIdx.x * 256 + threadIdx.x;
  float s = Wv[d];
#pragma unroll
  for (int p = 0; p < 16; ++p) s += w2p[(size_t)p * DDIM + d];
  wv2[d] = s;
}

// ============ small 128x128 2-phase GEMM (weight precompute only) ===========
template <int OUT_F32, int HAS_BIAS, int DO_TANH, int ZBATCH>
__global__ __launch_bounds__(256) void gemm_nt(
    const u16* __restrict__ A1, const u16* __restrict__ A2, int ksplit,
    const u16* __restrict__ Bw, const float* __restrict__ bias,
    void* __restrict__ Cout, int K, int lda, int ldb, int ldc,
    long long sA, long long sB, long long sC, int nm, int nn, int nz) {
  __shared__ u16 As[4096];
  __shared__ u16 Bs[4096];

  const int id = blockIdx.x;
  int bz, mb, nb;
  if (ZBATCH) {
    if ((nz & 7) == 0) {
      int x = id & 7; int j = id >> 3; int pb = nm * nn;
      bz = x + 8 * (j / pb);
      int in_ = j % pb; nb = in_ % nn; mb = in_ / nn;
    } else { bz = id % nz; int t = id / nz; nb = t % nn; mb = t / nn; }
  } else {
    bz = 0;
    if ((nm & 7) == 0) {
      int mg = id & 7; int t = id >> 3; int nmg = nm >> 3;
      nb = t % nn; mb = mg * nmg + t / nn;
    } else { nb = id % nn; mb = id / nn; }
  }

  const int tid = threadIdx.x;
  const int lane = tid & 63;
  const int wid = tid >> 6;
  const int wm = wid >> 1;
  const int wn = wid & 1;
  const int m0 = mb * 128;
  const int n0 = nb * 128;

  const u16* a1 = A1 + (size_t)bz * sA;
  const u16* a2 = A2 + (size_t)bz * sA;
  const u16* bw = Bw + (size_t)bz * sB;

  const int srow = wid * 16 + (lane >> 2);
  const int skof = (lane & 3) * 8;

  f32x4 acc[4][4] = {};

  for (int k0 = 0; k0 < K; k0 += 32) {
    const u16* ab; int kk;
    if (k0 < ksplit) { ab = a1; kk = k0; } else { ab = a2; kk = k0 - ksplit; }
    const u16* asrc = ab + (size_t)(m0 + srow) * lda + kk + skof;
    const u16* bsrc = bw + (size_t)(n0 + srow) * ldb + k0 + skof;
    gload_lds16(asrc, &As[wid * 512]);
    gload_lds16(asrc + (size_t)64 * lda, &As[2048 + wid * 512]);
    gload_lds16(bsrc, &Bs[wid * 512]);
    gload_lds16(bsrc + (size_t)64 * ldb, &Bs[2048 + wid * 512]);
    __syncthreads();

    bf16x8 af[4], bfv[4];
#pragma unroll
    for (int i = 0; i < 4; ++i) {
      af[i] = *(const bf16x8*)&As[(wm * 64 + i * 16 + (lane & 15)) * 32 + (lane >> 4) * 8];
      bfv[i] = *(const bf16x8*)&Bs[(wn * 64 + i * 16 + (lane & 15)) * 32 + (lane >> 4) * 8];
    }
#pragma unroll
    for (int i = 0; i < 4; ++i)
#pragma unroll
      for (int j = 0; j < 4; ++j)
        acc[i][j] = __builtin_amdgcn_mfma_f32_16x16x32_bf16(af[i], bfv[j], acc[i][j], 0, 0, 0);
    __syncthreads();
  }

  const int crow = (lane >> 4) * 4;
  const int ccol = lane & 15;
#pragma unroll
  for (int i = 0; i < 4; ++i) {
#pragma unroll
    for (int j = 0; j < 4; ++j) {
      int r0 = m0 + wm * 64 + i * 16 + crow;
      int c = n0 + wn * 64 + j * 16 + ccol;
      float bb = HAS_BIAS ? bias[c] : 0.f;
#pragma unroll
      for (int t = 0; t < 4; ++t) {
        float v = acc[i][j][t] + bb;
        if (DO_TANH) v = tanh_fast(v);
        size_t idx = (size_t)bz * sC + (size_t)(r0 + t) * ldc + c;
        if (OUT_F32) ((float*)Cout)[idx] = v;
        else ((u16*)Cout)[idx] = f2bf(v);
      }
    }
  }
}

// ======= 256x256 8-phase GEMM (round-8 schedule: per-phase barrier,
// counted vmcnt(4)/vmcnt(2), st swizzle). MASK bits: 1=skip dead m,
// 2=skip dead n, 4=truncate K. OUTT: 0=f32, 1=bf16, 2=f16.
// POOL=1: fused masked pooling epilogue (tanh + per-column sums -> pf),
// no C write. bias indexed bias[bz*sBias + c].
template <int OUTT, int HAS_BIAS, int DO_TANH, int ZBATCH, int MASK, int POOL>
__global__ __launch_bounds__(512, 1) void gemm8p(
    const u16* __restrict__ A1, const u16* __restrict__ A2, int ksplit,
    const u16* __restrict__ Bw, const float* __restrict__ bias, long long sBias,
    void* __restrict__ Cout, int K, int lda, int ldb, int ldc,
    long long sA, long long sB, long long sC, int nm, int nn, int nz,
    const int* __restrict__ lenb, float* __restrict__ pf) {
  __shared__ __align__(16) u16 A0[16384];
  __shared__ __align__(16) u16 A1s[16384];
  __shared__ __align__(16) u16 B0[16384];
  __shared__ __align__(16) u16 B1s[16384];

  const int id = blockIdx.x;
  int bz, mb, nb;
  if (ZBATCH) {
    if ((nz & 7) == 0) {
      int x = id & 7; int j = id >> 3; int pb = nm * nn;
      bz = x + 8 * (j / pb);
      int in_ = j % pb; nb = in_ % nn; mb = in_ / nn;
    } else { bz = id % nz; int t = id / nz; nb = t % nn; mb = t / nn; }
  } else {
    bz = 0;
    if ((nm & 7) == 0) {
      int mg = id & 7; int t = id >> 3; int nmg = nm >> 3;
      nb = t % nn; mb = mg * nmg + t / nn;
    } else { nb = id % nn; mb = id / nn; }
  }

  const int m0 = mb * 256;
  const int n0 = nb * 256;

  int Keff = K;
  if (MASK) {
    if (MASK & 1) {
      int lb = ZBATCH ? bz : (m0 >> 10);
      int lm = ZBATCH ? m0 : (m0 & 1023);
      if (lm >= lenb[lb]) return;
    }
    if (MASK & 2) {
      if (n0 >= lenb[bz]) return;
    }
    if (MASK & 4) {
      Keff = (lenb[bz] + 63) & ~63;
    }
  }
  const int NT = Keff >> 6;  // K-tiles of 64

  const int tid = threadIdx.x;
  const int lane = tid & 63;
  const int wid = tid >> 6;  // 0..7
  const int wm = wid >> 2;   // 0..1 : 128-row half
  const int wn = wid & 3;    // 0..3 : 64-col quarter

  const u16* a1 = A1 + (size_t)bz * sA;
  const u16* a2 = A2 + (size_t)bz * sA;
  const u16* bw = Bw + (size_t)bz * sB;

  const int stR = lane >> 3;
  const int stS = ((lane & 7) ^ (lane >> 3)) * 8;  // u16 units
  const int a1w = (wid < 4) ? wid : 4 + wid;
  const int a2w = (wid < 4) ? 4 + wid : 8 + wid;

  const int frr = lane & 15;
  const int fo0 = frr * 64 + (((lane >> 4)) ^ (frr & 7)) * 8;
  const int fo1 = frr * 64 + ((4 + (lane >> 4)) ^ (frr & 7)) * 8;

  f32x4 acc[8][4] = {};

#define STG_A(tt, buf, st)                                                   \
  do {                                                                       \
    int kb = (tt) << 6; const u16* g; int gk;                                \
    if (kb < ksplit) { g = a1; gk = kb; } else { g = a2; gk = kb - ksplit; } \
    const u16* src = g + (size_t)(m0 + (st) * 16 + stR) * lda + gk + stS;    \
    gload_lds16(src, (buf) + (st) * 1024);                                   \
    gload_lds16(src + (size_t)8 * lda, (buf) + (st) * 1024 + 512);           \
  } while (0)
#define STG_B(tt, buf, st)                                                   \
  do {                                                                       \
    int kb = (tt) << 6;                                                      \
    const u16* src = bw + (size_t)(n0 + (st) * 16 + stR) * ldb + kb + stS;   \
    gload_lds16(src, (buf) + (st) * 1024);                                   \
    gload_lds16(src + (size_t)8 * ldb, (buf) + (st) * 1024 + 512);           \
  } while (0)
#define BARR                                                                 \
  do {                                                                       \
    __builtin_amdgcn_s_barrier();                                            \
    asm volatile("s_waitcnt lgkmcnt(0)" ::: "memory");                       \
    __builtin_amdgcn_sched_barrier(0);                                       \
  } while (0)
#define MM(mb_)                                                              \
  do {                                                                       \
    __builtin_amdgcn_s_setprio(1);                                           \
    _Pragma("unroll") for (int mh = 0; mh < 2; ++mh)                         \
    _Pragma("unroll") for (int n = 0; n < 4; ++n) {                          \
      acc[(mb_) + mh][n] = __builtin_amdgcn_mfma_f32_16x16x32_bf16(          \
          afr[mh][0], bfr[n][0], acc[(mb_) + mh][n], 0, 0, 0);               \
      acc[(mb_) + mh][n] = __builtin_amdgcn_mfma_f32_16x16x32_bf16(          \
          afr[mh][1], bfr[n][1], acc[(mb_) + mh][n], 0, 0, 0);               \
    }                                                                        \
    __builtin_amdgcn_s_setprio(0);                                           \
  } while (0)
#define LDA2(Ab, mb_)                                                        \
  do {                                                                       \
    afr[0][0] = *(const bf16x8*)((Ab) + (wm * 8 + (mb_)) * 1024 + fo0);      \
    afr[0][1] = *(const bf16x8*)((Ab) + (wm * 8 + (mb_)) * 1024 + fo1);      \
    afr[1][0] = *(const bf16x8*)((Ab) + (wm * 8 + (mb_) + 1) * 1024 + fo0);  \
    afr[1][1] = *(const bf16x8*)((Ab) + (wm * 8 + (mb_) + 1) * 1024 + fo1);  \
  } while (0)

#define TILE(t, Ab, Bb, An, Bn)                                              \
  do {                                                                       \
    const bool stg = (t) + 1 < NT;                                           \
    bf16x8 bfr[4][2], afr[2][2];                                             \
    _Pragma("unroll") for (int n = 0; n < 4; ++n) {                          \
      bfr[n][0] = *(const bf16x8*)((Bb) + (wn * 4 + n) * 1024 + fo0);        \
      bfr[n][1] = *(const bf16x8*)((Bb) + (wn * 4 + n) * 1024 + fo1);        \
    }                                                                        \
    LDA2(Ab, 0);                                                             \
    if (stg) STG_B((t) + 1, Bn, wid);                                        \
    BARR; MM(0);                                                             \
    LDA2(Ab, 2);                                                             \
    if (stg) {                                                               \
      STG_B((t) + 1, Bn, 8 + wid);                                           \
      asm volatile("s_waitcnt vmcnt(4)" ::: "memory");                       \
    } else {                                                                 \
      asm volatile("s_waitcnt vmcnt(0)" ::: "memory");                       \
    }                                                                        \
    BARR; MM(2);                                                             \
    LDA2(Ab, 4);                                                             \
    if (stg) STG_A((t) + 1, An, a1w);                                        \
    BARR; MM(4);                                                             \
    LDA2(Ab, 6);                                                             \
    if (stg) {                                                               \
      STG_A((t) + 1, An, a2w);                                               \
      asm volatile("s_waitcnt vmcnt(2)" ::: "memory");                       \
    }                                                                        \
    BARR; MM(6);                                                             \
  } while (0)

  STG_A(0, A0, wid); STG_A(0, A0, wid + 8);
  STG_B(0, B0, wid); STG_B(0, B0, wid + 8);
  asm volatile("s_waitcnt vmcnt(0)" ::: "memory");
  __builtin_amdgcn_s_barrier();

  for (int t = 0; t < NT; t += 2) {
    TILE(t, A0, B0, A1s, B1s);
    if (t + 1 < NT) TILE(t + 1, A1s, B1s, A0, B0);
  }
#undef TILE
#undef LDA2
#undef MM
#undef BARR
#undef STG_A
#undef STG_B

  const int crow = (lane >> 4) * 4;
  const int ccol = lane & 15;

  if (POOL) {
    // fused masked pooling: per-column sums of tanh(acc + bias) over live rows
    const int b = m0 >> 10;
    const int lenv = lenb[b];
    const int qbase = (m0 & 1023) + wm * 128 + crow;
    float csum[4] = {0.f, 0.f, 0.f, 0.f};
#pragma unroll
    for (int j = 0; j < 4; ++j) {
      int c = n0 + wn * 64 + j * 16 + ccol;
      float bb = bias[c];
#pragma unroll
      for (int i = 0; i < 8; ++i) {
#pragma unroll
        for (int t = 0; t < 4; ++t) {
          int q = qbase + i * 16 + t;
          float v = tanh_fast(acc[i][j][t] + bb);
          csum[j] += (q < lenv) ? v : 0.f;
        }
      }
    }
    float* red = (float*)A0;  // [wm][wn][64] = 2 KB (LDS reuse after loop)
#pragma unroll
    for (int j = 0; j < 4; ++j) {
      float cs = csum[j];
      cs += __shfl_xor(cs, 16);
      cs += __shfl_xor(cs, 32);
      if (lane < 16) red[(wm * 4 + wn) * 64 + j * 16 + lane] = cs;
    }
    __syncthreads();
    if (tid < 256) {
      int wnn = tid >> 6, cl = tid & 63;
      float v = red[(0 * 4 + wnn) * 64 + cl] + red[(1 * 4 + wnn) * 64 + cl];
      pf[(size_t)mb * 1024 + n0 + wnn * 64 + cl] = v;
    }
    return;
  }

#pragma unroll
  for (int i = 0; i < 8; ++i) {
#pragma unroll
    for (int j = 0; j < 4; ++j) {
      int r0 = m0 + wm * 128 + i * 16 + crow;
      int c = n0 + wn * 64 + j * 16 + ccol;
      float bb = HAS_BIAS ? bias[(size_t)bz * sBias + c] : 0.f;
#pragma unroll
      for (int t = 0; t < 4; ++t) {
        float v = acc[i][j][t] + bb;
        if (DO_TANH) v = tanh_fast(v);
        size_t idx = (size_t)bz * sC + (size_t)(r0 + t) * ldc + c;
        if (OUTT == 0) {
          ((float*)Cout)[idx] = v;
        } else if (OUTT == 1) {
          ((u16*)Cout)[idx] = f2bf(v);
        } else {
          __half hv = __float2half(v);
          ((u16*)Cout)[idx] = __half_as_ushort(hv);
        }
      }
    }
  }
}

// -------- softmax over keys (mask); logits fp16 already include v-bias ------
__global__ __launch_bounds__(256) void softmax_rows(const u16* __restrict__ logits,
                                                    const int* __restrict__ amask,
                                                    u16* __restrict__ P,
                                                    const int* __restrict__ lenb) {
  const int row = blockIdx.x;  // blocal*L + q
  const int b = row >> 10;
  const int q = row & 1023;
  const int len = lenb[b];
  if (q >= len) return;  // dead query row: P never read downstream
  const int keff = (len + 63) & ~63;
  const u16* lg = logits + (size_t)row * LSEQ;
  u16* prow = P + (size_t)row * LSEQ;
  const int tid = threadIdx.x;
  const bool live = (tid * 4) < len;

  float x[4];
  int mk[4] = {0, 0, 0, 0};
  if (live) {
    ushort4 lraw = ((const ushort4*)lg)[tid];
    int4 mk4 = ((const int4*)(amask + (b << 10)))[tid];
    mk[0] = mk4.x; mk[1] = mk4.y; mk[2] = mk4.z; mk[3] = mk4.w;
    x[0] = __half2float(__ushort_as_half(lraw.x));
    x[1] = __half2float(__ushort_as_half(lraw.y));
    x[2] = __half2float(__ushort_as_half(lraw.z));
    x[3] = __half2float(__ushort_as_half(lraw.w));
  }

  float vmax = -3.0e38f;
#pragma unroll
  for (int i = 0; i < 4; ++i) {
    if (!mk[i]) x[i] = -3.0e38f;
    vmax = fmaxf(vmax, x[i]);
  }
#pragma unroll
  for (int o = 32; o; o >>= 1) vmax = fmaxf(vmax, __shfl_xor(vmax, o));
  __shared__ float sred[4];
  if ((tid & 63) == 0) sred[tid >> 6] = vmax;
  __syncthreads();
  vmax = fmaxf(fmaxf(sred[0], sred[1]), fmaxf(sred[2], sred[3]));
  float s = 0.f, e[4];
#pragma unroll
  for (int i = 0; i < 4; ++i) {
    e[i] = mk[i] ? __expf(x[i] - vmax) : 0.f;
    s += e[i];
  }
#pragma unroll
  for (int o = 32; o; o >>= 1) s += __shfl_xor(s, o);
  __shared__ float ssum[4];
  if ((tid & 63) == 0) ssum[tid >> 6] = s;
  __syncthreads();
  s = (ssum[0] + ssum[1]) + (ssum[2] + ssum[3]);
  float inv = 1.f / s;
  if ((tid * 4) < keff) {
    ushort4 o4;
    o4.x = f2bf(e[0] * inv);
    o4.y = f2bf(e[1] * inv);
    o4.z = f2bf(e[2] * inv);
    o4.w = f2bf(e[3] * inv);
    ((ushort4*)prow)[tid] = o4;
  }
}

// ------- final pooling: sum live pf chunks, divide by length -------
__global__ __launch_bounds__(256) void pool_final(const float* __restrict__ pf,
                                                  const int* __restrict__ lenb,
                                                  float* __restrict__ out) {
  int idx = blockIdx.x * 256 + threadIdx.x;  // b*D + d
  int b = idx >> 10;
  int d = idx & 1023;
  int len = lenb[b];
  float s = 0.f;
#pragma unroll
  for (int qc = 0; qc < 4; ++qc)
    if (qc * 256 < len) s += pf[(size_t)(b * 4 + qc) * 1024 + d];
  out[idx] = s / (float)len;
}

extern "C" void kernel_launch(void* const* d_in, const int* in_sizes, int n_in,
                              void* d_out, int out_size, void* d_ws, size_t ws_size,
                              hipStream_t stream) {
  const float* output = (const float*)d_in[0];
  const float* context = (const float*)d_in[1];
  const int* amask = (const int*)d_in[2];
  const float* Wo = (const float*)d_in[3];
  const float* bo = (const float*)d_in[4];
  const float* Wc = (const float*)d_in[5];
  const float* Wb = (const float*)d_in[7];
  const float* Wv = (const float*)d_in[10];
  const float* Wf = (const float*)d_in[12];
  const float* bfb = (const float*)d_in[13];
  float* out = (float*)d_out;
  (void)n_in; (void)in_sizes; (void)out_size;

  const size_t LD2 = (size_t)LSEQ * DDIM * 2;
  const size_t fixed_b = (size_t)24 * (1 << 20);
  const size_t per_b = 4 * LD2 + (size_t)LSEQ * LSEQ * 2 + 80 * LSEQ + 4096;
  int G = 1;
  for (int g : {32, 16, 8, 4, 2, 1}) {
    if (fixed_b + (size_t)g * per_b <= ws_size) { G = g; break; }
  }
  const int NG = BATCH / G;
  const int VN = G * LSEQ;

  char* ws = (char*)d_ws;
  size_t off = 0;
  auto alloc = [&](size_t bytes) {
    char* p = ws + off;
    off += (bytes + 255) & ~(size_t)255;
    return p;
  };
  const size_t W2 = (size_t)DDIM * DDIM * 2;
  u16* wb_bf = (u16*)alloc(W2);
  u16* wf_bf = (u16*)alloc(2 * W2);
  u16* woT_bf = (u16*)alloc(W2);
  u16* wcT_bf = (u16*)alloc(W2);
  u16* wboT_bf = (u16*)alloc(W2);
  u16* mt_bf = (u16*)alloc(W2);
  float* bbo = (float*)alloc(DDIM * 4);
  float* w2p = (float*)alloc((size_t)16 * DDIM * 4);
  float* wv2 = (float*)alloc(DDIM * 4);
  int* lenb = (int*)alloc(BATCH * 4);
  float* pf = (float*)alloc((size_t)BATCH * 4 * DDIM * 4);  // [B*4][1024]
  u16* out_g = (u16*)alloc((size_t)G * LD2);
  u16* ctx_g = (u16*)alloc((size_t)G * LD2);
  u16* ctxT_g = (u16*)alloc((size_t)G * LD2);
  u16* y_g = (u16*)alloc((size_t)G * LD2);
  u16* logits = (u16*)alloc((size_t)G * LSEQ * LSEQ * 2);  // fp16
  float* vbuf = (float*)alloc((size_t)VN * 4);
  float* vpart = (float*)alloc((size_t)16 * VN * 4);

  dim3 blk(256), blk8(512);
  const long long M1 = (long long)LSEQ * DDIM;
  const int BIG = 1 << 30;

  // ---- lengths + weight precompute ----
  len_kernel<<<dim3(BATCH), blk, 0, stream>>>(amask, lenb);
  cvt_kernel<<<dim3(1024), blk, 0, stream>>>(Wb, wb_bf, DDIM * DDIM / 4);
  cvt_kernel<<<dim3(2048), blk, 0, stream>>>(Wf, wf_bf, DDIM * 2 * DDIM / 4);
  transpose_w2<<<dim3(16, 16, 2), blk, 0, stream>>>(Wo, woT_bf, Wc, wcT_bf);
  rowdot_kernel<<<dim3(1024), blk, 0, stream>>>(Wb, bo, bbo);     // bbo = Wb@bo
  w2_part<<<dim3(4, 16), blk, 0, stream>>>(bbo, Wc, w2p);         // partials
  w2_red<<<dim3(4), blk, 0, stream>>>(Wv, w2p, wv2);              // wv2
  gemm_nt<0, 0, 0, 0><<<dim3(64), blk, 0, stream>>>(
      woT_bf, woT_bf, BIG, wb_bf, nullptr, wboT_bf,
      1024, 1024, 1024, 1024, 0, 0, 0, 8, 8, 1);
  gemm_nt<0, 0, 0, 0><<<dim3(64), blk, 0, stream>>>(
      wcT_bf, wcT_bf, BIG, wboT_bf, nullptr, mt_bf,
      1024, 1024, 1024, 1024, 0, 0, 0, 8, 8, 1);

  for (int grp = 0; grp < NG; ++grp) {
    const int gb = grp * G;
    const float* outp = output + (size_t)gb * LSEQ * DDIM;
    const float* ctxp = context + (size_t)gb * LSEQ * DDIM;
    const int* amp = amask + (size_t)gb * LSEQ;
    const int* lnp = lenb + gb;

    // fused prep: out cvt + ctx cvt + transpose + partial v-dot (masked)
    prep_kernel<<<dim3(16, 16, G), blk, 0, stream>>>(
        outp, ctxp, out_g, ctx_g, ctxT_g, wv2, vpart, VN, lnp);
    vred_kernel<<<dim3(VN / 256), blk, 0, stream>>>(vpart, vbuf, VN);

    // y = output @ M   [dense, bf16 out; skip dead q-blocks]
    gemm8p<1, 0, 0, 0, 1, 0><<<dim3(G * 16), blk8, 0, stream>>>(
        out_g, out_g, BIG, mt_bf, nullptr, 0, y_g,
        1024, 1024, 1024, 1024, 0, 0, 0, G * 4, 4, 1, lnp, nullptr);
    // logits[b] = y[b] @ ctx[b]^T + v[k]  [fp16 out; skip dead m,n blocks]
    gemm8p<2, 1, 0, 1, 3, 0><<<dim3(G * 16), blk8, 0, stream>>>(
        y_g, y_g, BIG, ctx_g, vbuf, 1024, logits,
        1024, 1024, 1024, 1024, M1, M1, M1, 4, 4, G, lnp, nullptr);
    // P = softmax(logits + mask) -> bf16 into y_g (skip dead rows)
    softmax_rows<<<dim3(G * LSEQ), blk, 0, stream>>>(logits, amp, y_g, lnp);
    // mix[b] = P[b] @ ctxT[b]^T -> bf16 into ctx_g (skip dead m; truncate K)
    gemm8p<1, 0, 0, 1, 5, 0><<<dim3(G * 16), blk8, 0, stream>>>(
        y_g, y_g, BIG, ctxT_g, nullptr, 0, ctx_g,
        1024, 1024, 1024, 1024, M1, M1, M1, 4, 4, G, lnp, nullptr);
    // fc + fused masked pooling: tanh([out, mix] @ Wf^T + bf) summed -> pf
    gemm8p<1, 1, 1, 0, 1, 1><<<dim3(G * 16), blk8, 0, stream>>>(
        out_g, ctx_g, 1024, wf_bf, bfb, 0, nullptr,
        2048, 1024, 2048, 1024, 0, 0, 0, G * 4, 4, 1, lnp,
        pf + (size_t)gb * 4 * DDIM);
  }
  pool_final<<<dim3(128), blk, 0, stream>>>(pf, lenb, out);
}